// Round 1
// baseline (1687.389 us; speedup 1.0000x reference)
//
#include <hip/hip_runtime.h>
#include <math.h>

#define NN 100000
#define NE 1600000

__device__ inline void atomAddF(float* p, float v) {
    __hip_atomic_fetch_add(p, v, __ATOMIC_RELAXED, __HIP_MEMORY_SCOPE_AGENT);
}

__device__ inline void atomicMaxF(float* addr, float val) {
    if (val >= 0.f) atomicMax((int*)addr, __float_as_int(val));
    else            atomicMin((unsigned int*)addr, __float_as_uint(val));
}

// wdot[h] = sum_c We1[h*32+c]*ae1[h*32+c]  (h<4);  wdot[4] = sum_c We2[c]*ae2[c]
__global__ void k_prep(const float* __restrict__ We1, const float* __restrict__ ae1,
                       const float* __restrict__ We2, const float* __restrict__ ae2,
                       float* __restrict__ wdot) {
    int t = threadIdx.x;
    if (t < 4) {
        float s = 0.f;
        for (int c = 0; c < 32; ++c) s += We1[t*32+c] * ae1[t*32+c];
        wdot[t] = s;
    } else if (t == 4) {
        float s = 0.f;
        for (int c = 0; c < 32; ++c) s += We2[c] * ae2[c];
        wdot[4] = s;
    }
}

__global__ void k_enorm(const float* __restrict__ ea, const float* __restrict__ g,
                        const float* __restrict__ b, const float* __restrict__ m,
                        const float* __restrict__ v, float* __restrict__ e_n) {
    int i = blockIdx.x * blockDim.x + threadIdx.x;
    if (i < NE)
        e_n[i] = (log1pf(ea[i]) - m[0]) * rsqrtf(v[0] + 1e-5f) * g[0] + b[0];
}

// per node: h1 = x@W1 (128ch), alpha_src/dst per head, init amax/den/acc
__global__ void k1_node1(const float* __restrict__ x, const float* __restrict__ W1,
                         const float* __restrict__ as1, const float* __restrict__ ad1,
                         float* __restrict__ h1, float* __restrict__ as1n,
                         float* __restrict__ ad1n, float* __restrict__ amax1,
                         float* __restrict__ den1, float* __restrict__ acc1) {
    __shared__ float W1s[64*128];
    __shared__ float as1s[128], ad1s[128];
    __shared__ float xrow[64];
    int tid = threadIdx.x;  // 128
    for (int i = tid; i < 64*128; i += 128) W1s[i] = W1[i];
    as1s[tid] = as1[tid];
    ad1s[tid] = ad1[tid];
    __syncthreads();
    for (int n = blockIdx.x; n < NN; n += gridDim.x) {
        if (tid < 64) xrow[tid] = x[n*64 + tid];
        __syncthreads();
        float v = 0.f;
        #pragma unroll
        for (int k = 0; k < 64; ++k) v = fmaf(xrow[k], W1s[k*128 + tid], v);
        h1[n*128 + tid]  = v;
        acc1[n*128 + tid] = 0.f;
        float av = v * as1s[tid];
        float dv = v * ad1s[tid];
        #pragma unroll
        for (int d = 16; d; d >>= 1) {
            av += __shfl_xor(av, d, 32);
            dv += __shfl_xor(dv, d, 32);
        }
        if ((tid & 31) == 0) {
            int h = tid >> 5;
            as1n[n*4 + h]  = av;
            ad1n[n*4 + h]  = dv;
            amax1[n*4 + h] = -INFINITY;
            den1[n*4 + h]  = 0.f;
        }
        __syncthreads();
    }
}

// per edge: alpha per head + atomicMax into amax1[dst]
__global__ void k2_edge1a(const int* __restrict__ ei, const float* __restrict__ e_n,
                          const float* __restrict__ as1n, const float* __restrict__ ad1n,
                          const float* __restrict__ wdot, float* __restrict__ amax1) {
    int e = blockIdx.x * blockDim.x + threadIdx.x;
    if (e >= NE) return;
    int src = ei[e], dst = ei[NE + e];
    float en = e_n[e];
    #pragma unroll
    for (int h = 0; h < 4; ++h) {
        float a = as1n[src*4+h] + ad1n[dst*4+h] + en * wdot[h];
        a = a > 0.f ? a : 0.2f * a;
        atomicMaxF(&amax1[dst*4+h], a);
    }
}

__global__ void k_fixmax(float* __restrict__ amax, int n) {
    int i = blockIdx.x * blockDim.x + threadIdx.x;
    if (i < n) {
        float v = amax[i];
        amax[i] = isfinite(v) ? v : 0.f;
    }
}

// one wave per edge: ex = exp(alpha - amax); den += ex; acc[dst] += ex*h1[src]
__global__ void k4_edge1b(const int* __restrict__ ei, const float* __restrict__ e_n,
                          const float* __restrict__ as1n, const float* __restrict__ ad1n,
                          const float* __restrict__ amax1, const float* __restrict__ wdot,
                          const float* __restrict__ h1, float* __restrict__ den1,
                          float* __restrict__ acc1) {
    int wave = threadIdx.x >> 6;
    int lane = threadIdx.x & 63;
    int e = blockIdx.x * 4 + wave;
    if (e >= NE) return;
    int src = ei[e], dst = ei[NE + e];
    float en = e_n[e];
    int h0 = lane >> 5;   // head for channel `lane`
    int h1i = h0 + 2;     // head for channel `lane+64`
    float a0 = as1n[src*4+h0] + ad1n[dst*4+h0] + en * wdot[h0];
    a0 = a0 > 0.f ? a0 : 0.2f * a0;
    float ex0 = expf(a0 - amax1[dst*4+h0]);
    float a1 = as1n[src*4+h1i] + ad1n[dst*4+h1i] + en * wdot[h1i];
    a1 = a1 > 0.f ? a1 : 0.2f * a1;
    float ex1 = expf(a1 - amax1[dst*4+h1i]);
    if ((lane & 31) == 0) {
        atomAddF(&den1[dst*4+h0],  ex0);
        atomAddF(&den1[dst*4+h1i], ex1);
    }
    atomAddF(&acc1[dst*128 + lane],      ex0 * h1[src*128 + lane]);
    atomAddF(&acc1[dst*128 + 64 + lane], ex1 * h1[src*128 + 64 + lane]);
}

// node epilogue L1 (softmax divide + bias + ELU) fused with L2 node transform
__global__ void k5_node2(const float* __restrict__ acc1, const float* __restrict__ den1,
                         const float* __restrict__ b1, const float* __restrict__ W2,
                         const float* __restrict__ as2, const float* __restrict__ ad2,
                         float* __restrict__ h2, float* __restrict__ as2n,
                         float* __restrict__ ad2n, float* __restrict__ amax2,
                         float* __restrict__ den2, float* __restrict__ acc2) {
    __shared__ float W2s[128*32];
    __shared__ float h1e[128];
    __shared__ float as2s[32], ad2s[32], b1s[128];
    int tid = threadIdx.x;  // 128
    for (int i = tid; i < 128*32; i += 128) W2s[i] = W2[i];
    if (tid < 32) { as2s[tid] = as2[tid]; ad2s[tid] = ad2[tid]; }
    b1s[tid] = b1[tid];
    __syncthreads();
    for (int n = blockIdx.x; n < NN; n += gridDim.x) {
        float v = acc1[n*128+tid] / (den1[n*4 + (tid>>5)] + 1e-16f) + b1s[tid];
        v = v > 0.f ? v : expm1f(v);   // ELU
        h1e[tid] = v;
        __syncthreads();
        if (tid < 32) {
            float s = 0.f;
            #pragma unroll
            for (int k = 0; k < 128; ++k) s = fmaf(h1e[k], W2s[k*32 + tid], s);
            h2[n*32 + tid]   = s;
            acc2[n*32 + tid] = 0.f;
            float av = s * as2s[tid], dv = s * ad2s[tid];
            #pragma unroll
            for (int d = 16; d; d >>= 1) {
                av += __shfl_xor(av, d, 32);
                dv += __shfl_xor(dv, d, 32);
            }
            if (tid == 0) {
                as2n[n] = av; ad2n[n] = dv;
                amax2[n] = -INFINITY; den2[n] = 0.f;
            }
        }
        __syncthreads();
    }
}

__global__ void k6_edge2a(const int* __restrict__ ei, const float* __restrict__ e_n,
                          const float* __restrict__ as2n, const float* __restrict__ ad2n,
                          const float* __restrict__ wdot, float* __restrict__ amax2) {
    int e = blockIdx.x * blockDim.x + threadIdx.x;
    if (e >= NE) return;
    int src = ei[e], dst = ei[NE + e];
    float a = as2n[src] + ad2n[dst] + e_n[e] * wdot[4];
    a = a > 0.f ? a : 0.2f * a;
    atomicMaxF(&amax2[dst], a);
}

// 32 lanes per edge
__global__ void k8_edge2b(const int* __restrict__ ei, const float* __restrict__ e_n,
                          const float* __restrict__ as2n, const float* __restrict__ ad2n,
                          const float* __restrict__ amax2, const float* __restrict__ wdot,
                          const float* __restrict__ h2, float* __restrict__ den2,
                          float* __restrict__ acc2) {
    int sub  = threadIdx.x >> 5;
    int lane = threadIdx.x & 31;
    int e = blockIdx.x * 8 + sub;
    if (e >= NE) return;
    int src = ei[e], dst = ei[NE + e];
    float a = as2n[src] + ad2n[dst] + e_n[e] * wdot[4];
    a = a > 0.f ? a : 0.2f * a;
    float ex = expf(a - amax2[dst]);
    if (lane == 0) atomAddF(&den2[dst], ex);
    atomAddF(&acc2[dst*32 + lane], ex * h2[src*32 + lane]);
}

// z = acc2/den2 + b2  -> out[0:N*32];  x_hat = elu(z@Wd1+bd1)@Wd2+bd2 -> out[N*32:]
__global__ void k9_dec(const float* __restrict__ acc2, const float* __restrict__ den2,
                       const float* __restrict__ b2, const float* __restrict__ Wd1,
                       const float* __restrict__ bd1, const float* __restrict__ Wd2,
                       const float* __restrict__ bd2, float* __restrict__ out) {
    __shared__ float Wd1s[32*32], Wd2s[32*64];
    __shared__ float bd1s[32], bd2s[64], b2s[32];
    __shared__ float zs[32], ts[32];
    int tid = threadIdx.x;  // 64
    for (int i = tid; i < 1024; i += 64) Wd1s[i] = Wd1[i];
    for (int i = tid; i < 2048; i += 64) Wd2s[i] = Wd2[i];
    if (tid < 32) { bd1s[tid] = bd1[tid]; b2s[tid] = b2[tid]; }
    bd2s[tid] = bd2[tid];
    __syncthreads();
    for (int n = blockIdx.x; n < NN; n += gridDim.x) {
        if (tid < 32) {
            float z = acc2[n*32+tid] / (den2[n] + 1e-16f) + b2s[tid];
            out[n*32 + tid] = z;
            zs[tid] = z;
        }
        __syncthreads();
        if (tid < 32) {
            float t = bd1s[tid];
            #pragma unroll
            for (int j = 0; j < 32; ++j) t = fmaf(zs[j], Wd1s[j*32 + tid], t);
            t = t > 0.f ? t : expm1f(t);   // ELU
            ts[tid] = t;
        }
        __syncthreads();
        float xo = bd2s[tid];
        #pragma unroll
        for (int k = 0; k < 32; ++k) xo = fmaf(ts[k], Wd2s[k*64 + tid], xo);
        out[NN*32 + n*64 + tid] = xo;
        __syncthreads();
    }
}

extern "C" void kernel_launch(void* const* d_in, const int* in_sizes, int n_in,
                              void* d_out, int out_size, void* d_ws, size_t ws_size,
                              hipStream_t stream) {
    const float* x    = (const float*)d_in[0];
    const int*   ei   = (const int*)  d_in[1];
    const float* ea   = (const float*)d_in[2];
    const float* bng  = (const float*)d_in[3];
    const float* bnb  = (const float*)d_in[4];
    const float* bnm  = (const float*)d_in[5];
    const float* bnv  = (const float*)d_in[6];
    const float* W1   = (const float*)d_in[7];
    const float* as1  = (const float*)d_in[8];
    const float* ad1  = (const float*)d_in[9];
    const float* We1  = (const float*)d_in[10];
    const float* ae1  = (const float*)d_in[11];
    const float* b1   = (const float*)d_in[12];
    const float* W2   = (const float*)d_in[13];
    const float* as2  = (const float*)d_in[14];
    const float* ad2  = (const float*)d_in[15];
    const float* We2  = (const float*)d_in[16];
    const float* ae2  = (const float*)d_in[17];
    const float* b2   = (const float*)d_in[18];
    const float* Wd1  = (const float*)d_in[19];
    const float* bd1  = (const float*)d_in[20];
    const float* Wd2  = (const float*)d_in[21];
    const float* bd2  = (const float*)d_in[22];
    float* out = (float*)d_out;

    float* ws = (float*)d_ws;
    float* e_n   = ws;                       // NE
    float* h1    = e_n   + NE;               // NN*128
    float* as1n  = h1    + (size_t)NN*128;   // NN*4
    float* ad1n  = as1n  + (size_t)NN*4;     // NN*4
    float* amax1 = ad1n  + (size_t)NN*4;     // NN*4
    float* den1  = amax1 + (size_t)NN*4;     // NN*4
    float* acc1  = den1  + (size_t)NN*4;     // NN*128
    float* wdot  = acc1  + (size_t)NN*128;   // 8
    // layer-2 buffers aliased into h1 region (h1 dead after k4)
    float* h2    = h1;                       // NN*32
    float* as2n  = h1   + (size_t)NN*32;     // NN
    float* ad2n  = as2n + NN;                // NN
    float* amax2 = ad2n + NN;                // NN
    float* den2  = amax2 + NN;               // NN
    float* acc2  = den2  + NN;               // NN*32

    hipLaunchKernelGGL(k_prep, dim3(1), dim3(64), 0, stream, We1, ae1, We2, ae2, wdot);
    hipLaunchKernelGGL(k_enorm, dim3((NE+255)/256), dim3(256), 0, stream,
                       ea, bng, bnb, bnm, bnv, e_n);
    hipLaunchKernelGGL(k1_node1, dim3(2048), dim3(128), 0, stream,
                       x, W1, as1, ad1, h1, as1n, ad1n, amax1, den1, acc1);
    hipLaunchKernelGGL(k2_edge1a, dim3((NE+255)/256), dim3(256), 0, stream,
                       ei, e_n, as1n, ad1n, wdot, amax1);
    hipLaunchKernelGGL(k_fixmax, dim3((NN*4+255)/256), dim3(256), 0, stream, amax1, NN*4);
    hipLaunchKernelGGL(k4_edge1b, dim3(NE/4), dim3(256), 0, stream,
                       ei, e_n, as1n, ad1n, amax1, wdot, h1, den1, acc1);
    hipLaunchKernelGGL(k5_node2, dim3(2048), dim3(128), 0, stream,
                       acc1, den1, b1, W2, as2, ad2, h2, as2n, ad2n, amax2, den2, acc2);
    hipLaunchKernelGGL(k6_edge2a, dim3((NE+255)/256), dim3(256), 0, stream,
                       ei, e_n, as2n, ad2n, wdot, amax2);
    hipLaunchKernelGGL(k_fixmax, dim3((NN+255)/256), dim3(256), 0, stream, amax2, NN);
    hipLaunchKernelGGL(k8_edge2b, dim3(NE/8), dim3(256), 0, stream,
                       ei, e_n, as2n, ad2n, amax2, wdot, h2, den2, acc2);
    hipLaunchKernelGGL(k9_dec, dim3(2048), dim3(64), 0, stream,
                       acc2, den2, b2, Wd1, bd1, Wd2, bd2, out);
}

// Round 2
// 926.219 us; speedup vs baseline: 1.8218x; 1.8218x over previous
//
#include <hip/hip_runtime.h>
#include <math.h>

#define NN 100000
#define NE 1600000

// ---------- tiny prep: wdot[h] = <We1_h, ae1_h>, wdot[4] = <We2, ae2> ----------
__global__ void k_prep(const float* __restrict__ We1, const float* __restrict__ ae1,
                       const float* __restrict__ We2, const float* __restrict__ ae2,
                       float* __restrict__ wdot) {
    int t = threadIdx.x;
    if (t < 4) {
        float s = 0.f;
        for (int c = 0; c < 32; ++c) s += We1[t*32+c] * ae1[t*32+c];
        wdot[t] = s;
    } else if (t == 4) {
        float s = 0.f;
        for (int c = 0; c < 32; ++c) s += We2[c] * ae2[c];
        wdot[4] = s;
    }
}

// ---------- CSR build ----------
__global__ void k_zero(int* __restrict__ counts) {
    int i = blockIdx.x * blockDim.x + threadIdx.x;
    if (i < NN) counts[i] = 0;
}

__global__ void k_hist(const int* __restrict__ ei, int* __restrict__ counts) {
    int e = blockIdx.x * blockDim.x + threadIdx.x;
    if (e < NE) atomicAdd(&counts[ei[NE + e]], 1);
}

// single block, 1024 threads: exclusive scan of counts -> rowptr, cursor
__global__ void k_scan(const int* __restrict__ counts, int* __restrict__ rowptr,
                       int* __restrict__ cursor) {
    __shared__ int lds[1024];
    const int CH = (NN + 1023) / 1024;   // 98
    int t = threadIdx.x;
    int base = t * CH;
    int end  = min(base + CH, NN);
    int sum = 0;
    for (int i = base; i < end; ++i) sum += counts[i];
    lds[t] = sum;
    __syncthreads();
    for (int d = 1; d < 1024; d <<= 1) {
        int v = (t >= d) ? lds[t - d] : 0;
        __syncthreads();
        lds[t] += v;
        __syncthreads();
    }
    int run = (t == 0) ? 0 : lds[t - 1];
    for (int i = base; i < end; ++i) {
        rowptr[i] = run;
        cursor[i] = run;
        run += counts[i];
    }
    if (t == 0) rowptr[NN] = NE;
}

// scatter edges into dst-sorted order; fuse edge BN/log1p transform
__global__ void k_scatter(const int* __restrict__ ei, const float* __restrict__ ea,
                          const float* __restrict__ g, const float* __restrict__ b,
                          const float* __restrict__ m, const float* __restrict__ v,
                          int* __restrict__ cursor, int* __restrict__ src_s,
                          float* __restrict__ en_s) {
    int e = blockIdx.x * blockDim.x + threadIdx.x;
    if (e >= NE) return;
    int dst = ei[NE + e];
    int pos = atomicAdd(&cursor[dst], 1);
    src_s[pos] = ei[e];
    en_s[pos] = (log1pf(ea[e]) - m[0]) * rsqrtf(v[0] + 1e-5f) * g[0] + b[0];
}

// ---------- node transform layer 1: h1 = x@W1, alpha_src/dst per head ----------
__global__ void k1_node1(const float* __restrict__ x, const float* __restrict__ W1,
                         const float* __restrict__ as1, const float* __restrict__ ad1,
                         float* __restrict__ h1, float* __restrict__ as1n,
                         float* __restrict__ ad1n) {
    __shared__ float W1s[64*128];
    __shared__ float as1s[128], ad1s[128];
    __shared__ float xrow[64];
    int tid = threadIdx.x;  // 128
    for (int i = tid; i < 64*128; i += 128) W1s[i] = W1[i];
    as1s[tid] = as1[tid];
    ad1s[tid] = ad1[tid];
    __syncthreads();
    for (int n = blockIdx.x; n < NN; n += gridDim.x) {
        if (tid < 64) xrow[tid] = x[n*64 + tid];
        __syncthreads();
        float v = 0.f;
        #pragma unroll
        for (int k = 0; k < 64; ++k) v = fmaf(xrow[k], W1s[k*128 + tid], v);
        h1[(size_t)n*128 + tid] = v;
        float av = v * as1s[tid];
        float dv = v * ad1s[tid];
        #pragma unroll
        for (int d = 16; d; d >>= 1) {
            av += __shfl_xor(av, d, 32);
            dv += __shfl_xor(dv, d, 32);
        }
        if ((tid & 31) == 0) {
            int h = tid >> 5;
            as1n[n*4 + h] = av;
            ad1n[n*4 + h] = dv;
        }
        __syncthreads();
    }
}

// ---------- layer-1 aggregate (CSR, one wave per node) + epilogue + h@W2 ----------
__global__ void __launch_bounds__(256)
kA1(const int* __restrict__ rowptr, const int* __restrict__ src_s,
    const float* __restrict__ en_s, const float* __restrict__ as1n,
    const float* __restrict__ ad1n, const float* __restrict__ wdot,
    const float* __restrict__ h1, const float* __restrict__ b1,
    const float* __restrict__ W2, const float* __restrict__ as2,
    const float* __restrict__ ad2, float* __restrict__ h2,
    float* __restrict__ as2n, float* __restrict__ ad2n) {
    __shared__ float W2s[128*32];
    __shared__ float slot[4][128];
    __shared__ float as2s[32], ad2s[32], b1s[128];
    int tid = threadIdx.x;          // 256
    int wid = tid >> 6;             // wave in block
    int lane = tid & 63;
    for (int i = tid; i < 128*32; i += 256) W2s[i] = W2[i];
    if (tid < 32) { as2s[tid] = as2[tid]; ad2s[tid] = ad2[tid]; }
    if (tid < 128) b1s[tid] = b1[tid];
    __syncthreads();

    int n = blockIdx.x * 4 + wid;
    if (n >= NN) return;

    int row0 = rowptr[n], row1 = rowptr[n + 1];
    float4 wd  = *(const float4*)wdot;
    float4 adv = *(const float4*)&ad1n[n*4];

    // pass 1: per-head max over incident edges (lane-strided)
    float m0 = -INFINITY, m1 = -INFINITY, m2 = -INFINITY, m3 = -INFINITY;
    for (int j = row0 + lane; j < row1; j += 64) {
        int s = src_s[j];
        float en = en_s[j];
        float4 asv = *(const float4*)&as1n[s*4];
        float a0 = asv.x + adv.x + en * wd.x; a0 = a0 > 0.f ? a0 : 0.2f*a0;
        float a1 = asv.y + adv.y + en * wd.y; a1 = a1 > 0.f ? a1 : 0.2f*a1;
        float a2 = asv.z + adv.z + en * wd.z; a2 = a2 > 0.f ? a2 : 0.2f*a2;
        float a3 = asv.w + adv.w + en * wd.w; a3 = a3 > 0.f ? a3 : 0.2f*a3;
        m0 = fmaxf(m0, a0); m1 = fmaxf(m1, a1);
        m2 = fmaxf(m2, a2); m3 = fmaxf(m3, a3);
    }
    #pragma unroll
    for (int d = 32; d; d >>= 1) {
        m0 = fmaxf(m0, __shfl_xor(m0, d));
        m1 = fmaxf(m1, __shfl_xor(m1, d));
        m2 = fmaxf(m2, __shfl_xor(m2, d));
        m3 = fmaxf(m3, __shfl_xor(m3, d));
    }

    // pass 2: exp + denom + weighted accumulate (whole wave per edge)
    int h03 = lane & 3;          // head this lane's exp covers
    int hc0 = lane >> 5;         // head of channel `lane` (0/1); channel lane+64 -> hc0+2
    float mh  = (h03 == 0) ? m0 : (h03 == 1) ? m1 : (h03 == 2) ? m2 : m3;
    float adh = (h03 == 0) ? adv.x : (h03 == 1) ? adv.y : (h03 == 2) ? adv.z : adv.w;
    float wdh = (h03 == 0) ? wd.x : (h03 == 1) ? wd.y : (h03 == 2) ? wd.z : wd.w;
    float den = 0.f, acc0 = 0.f, acc1v = 0.f;
    for (int j = row0; j < row1; ++j) {
        int s = src_s[j];
        float en = en_s[j];
        float a = as1n[s*4 + h03] + adh + en * wdh;
        a = a > 0.f ? a : 0.2f*a;
        float ex = __expf(a - mh);
        den += ex;
        float ex0 = __shfl(ex, hc0);
        float ex1 = __shfl(ex, hc0 + 2);
        const float* hp = &h1[(size_t)s * 128];
        acc0  = fmaf(ex0, hp[lane],      acc0);
        acc1v = fmaf(ex1, hp[lane + 64], acc1v);
    }
    float den0 = __shfl(den, hc0);
    float den1 = __shfl(den, hc0 + 2);
    float o0 = acc0  / (den0 + 1e-16f) + b1s[lane];
    float o1 = acc1v / (den1 + 1e-16f) + b1s[lane + 64];
    o0 = o0 > 0.f ? o0 : expm1f(o0);
    o1 = o1 > 0.f ? o1 : expm1f(o1);
    slot[wid][lane]      = o0;
    slot[wid][lane + 64] = o1;
    // wave-local LDS: same-wave ds ops are in-order; no barrier needed

    // h2 = elu(out1) @ W2  (k-split across wave halves)
    int c  = lane & 31;
    int k0 = (lane >> 5) * 64;
    float s2 = 0.f;
    #pragma unroll
    for (int k = 0; k < 64; ++k)
        s2 = fmaf(slot[wid][k0 + k], W2s[(k0 + k)*32 + c], s2);
    s2 += __shfl_xor(s2, 32);
    if (lane < 32) h2[(size_t)n*32 + c] = s2;
    float av = s2 * as2s[c] * 0.5f;   // each channel duplicated in both halves
    float dv = s2 * ad2s[c] * 0.5f;
    #pragma unroll
    for (int d = 32; d; d >>= 1) {
        av += __shfl_xor(av, d);
        dv += __shfl_xor(dv, d);
    }
    if (lane == 0) { as2n[n] = av; ad2n[n] = dv; }
}

// ---------- layer-2 aggregate (CSR, one wave per node) + z + decoder MLP ----------
__global__ void __launch_bounds__(256)
kA2(const int* __restrict__ rowptr, const int* __restrict__ src_s,
    const float* __restrict__ en_s, const float* __restrict__ as2n,
    const float* __restrict__ ad2n, const float* __restrict__ wdot,
    const float* __restrict__ h2, const float* __restrict__ b2,
    const float* __restrict__ Wd1, const float* __restrict__ bd1,
    const float* __restrict__ Wd2, const float* __restrict__ bd2,
    float* __restrict__ out) {
    __shared__ float Wd1s[32*32], Wd2s[32*64];
    __shared__ float zs[4][32], ts[4][32];
    __shared__ float b2s[32], bd1s[32], bd2s[64];
    int tid = threadIdx.x;   // 256
    int wid = tid >> 6;
    int lane = tid & 63;
    for (int i = tid; i < 1024; i += 256) Wd1s[i] = Wd1[i];
    for (int i = tid; i < 2048; i += 256) Wd2s[i] = Wd2[i];
    if (tid < 32) { b2s[tid] = b2[tid]; bd1s[tid] = bd1[tid]; }
    if (tid < 64) bd2s[tid] = bd2[tid];
    __syncthreads();

    int n = blockIdx.x * 4 + wid;
    if (n >= NN) return;

    int row0 = rowptr[n], row1 = rowptr[n + 1];
    float wd4 = wdot[4];
    float adn = ad2n[n];

    // pass 1: max (lane-strided)
    float m = -INFINITY;
    for (int j = row0 + lane; j < row1; j += 64) {
        float a = as2n[src_s[j]] + adn + en_s[j] * wd4;
        a = a > 0.f ? a : 0.2f*a;
        m = fmaxf(m, a);
    }
    #pragma unroll
    for (int d = 32; d; d >>= 1) m = fmaxf(m, __shfl_xor(m, d));

    // pass 2: two half-waves process alternating edges
    int half = lane >> 5;
    int l5 = lane & 31;
    float den = 0.f, acc = 0.f;
    for (int j = row0 + half; j < row1; j += 2) {
        int s = src_s[j];
        float a = as2n[s] + adn + en_s[j] * wd4;
        a = a > 0.f ? a : 0.2f*a;
        float ex = __expf(a - m);
        den += ex;
        acc = fmaf(ex, h2[(size_t)s*32 + l5], acc);
    }
    den += __shfl_xor(den, 32);   // halves summed disjoint edge sets
    acc += __shfl_xor(acc, 32);
    float z = acc / (den + 1e-16f) + b2s[l5];
    if (lane < 32) {
        out[(size_t)n*32 + l5] = z;
        zs[wid][l5] = z;
    }

    // decoder: t = elu(z@Wd1+bd1); x_hat = t@Wd2+bd2
    int kk0 = half * 16;
    float t = 0.f;
    #pragma unroll
    for (int k = 0; k < 16; ++k)
        t = fmaf(zs[wid][kk0 + k], Wd1s[(kk0 + k)*32 + l5], t);
    t += __shfl_xor(t, 32);
    t += bd1s[l5];
    t = t > 0.f ? t : expm1f(t);
    if (lane < 32) ts[wid][l5] = t;

    float xo = bd2s[lane];
    #pragma unroll
    for (int k = 0; k < 32; ++k)
        xo = fmaf(ts[wid][k], Wd2s[k*64 + lane], xo);
    out[(size_t)NN*32 + (size_t)n*64 + lane] = xo;
}

extern "C" void kernel_launch(void* const* d_in, const int* in_sizes, int n_in,
                              void* d_out, int out_size, void* d_ws, size_t ws_size,
                              hipStream_t stream) {
    const float* x    = (const float*)d_in[0];
    const int*   ei   = (const int*)  d_in[1];
    const float* ea   = (const float*)d_in[2];
    const float* bng  = (const float*)d_in[3];
    const float* bnb  = (const float*)d_in[4];
    const float* bnm  = (const float*)d_in[5];
    const float* bnv  = (const float*)d_in[6];
    const float* W1   = (const float*)d_in[7];
    const float* as1  = (const float*)d_in[8];
    const float* ad1  = (const float*)d_in[9];
    const float* We1  = (const float*)d_in[10];
    const float* ae1  = (const float*)d_in[11];
    const float* b1   = (const float*)d_in[12];
    const float* W2   = (const float*)d_in[13];
    const float* as2  = (const float*)d_in[14];
    const float* ad2  = (const float*)d_in[15];
    const float* We2  = (const float*)d_in[16];
    const float* ae2  = (const float*)d_in[17];
    const float* b2   = (const float*)d_in[18];
    const float* Wd1  = (const float*)d_in[19];
    const float* bd1  = (const float*)d_in[20];
    const float* Wd2  = (const float*)d_in[21];
    const float* bd2  = (const float*)d_in[22];
    float* out = (float*)d_out;

    float* wsf   = (float*)d_ws;
    float* h1    = wsf;                       // NN*128
    float* as1n  = h1    + (size_t)NN*128;    // NN*4
    float* ad1n  = as1n  + (size_t)NN*4;      // NN*4
    float* h2    = ad1n  + (size_t)NN*4;      // NN*32
    float* as2n  = h2    + (size_t)NN*32;     // NN
    float* ad2n  = as2n  + NN;                // NN
    float* en_s  = ad2n  + NN;                // NE
    float* wdot  = en_s  + NE;                // 8
    int*   counts = (int*)(wdot + 8);         // NN
    int*   rowptr = counts + NN;              // NN+1
    int*   cursor = rowptr + NN + 1;          // NN
    int*   src_s  = cursor + NN;              // NE

    hipLaunchKernelGGL(k_prep, dim3(1), dim3(64), 0, stream, We1, ae1, We2, ae2, wdot);
    hipLaunchKernelGGL(k_zero, dim3((NN+255)/256), dim3(256), 0, stream, counts);
    hipLaunchKernelGGL(k_hist, dim3((NE+255)/256), dim3(256), 0, stream, ei, counts);
    hipLaunchKernelGGL(k_scan, dim3(1), dim3(1024), 0, stream, counts, rowptr, cursor);
    hipLaunchKernelGGL(k_scatter, dim3((NE+255)/256), dim3(256), 0, stream,
                       ei, ea, bng, bnb, bnm, bnv, cursor, src_s, en_s);
    hipLaunchKernelGGL(k1_node1, dim3(2048), dim3(128), 0, stream,
                       x, W1, as1, ad1, h1, as1n, ad1n);
    hipLaunchKernelGGL(kA1, dim3((NN+3)/4), dim3(256), 0, stream,
                       rowptr, src_s, en_s, as1n, ad1n, wdot, h1, b1, W2, as2, ad2,
                       h2, as2n, ad2n);
    hipLaunchKernelGGL(kA2, dim3((NN+3)/4), dim3(256), 0, stream,
                       rowptr, src_s, en_s, as2n, ad2n, wdot, h2, b2, Wd1, bd1, Wd2, bd2,
                       out);
}

// Round 3
// 614.054 us; speedup vs baseline: 2.7479x; 1.5084x over previous
//
#include <hip/hip_runtime.h>
#include <math.h>

#define NN 100000
#define NE 1600000

// ---------- CSR build: hist with rank recording ----------
__global__ void k_hist(const int* __restrict__ ei, int* __restrict__ counts,
                       int* __restrict__ rank) {
    int e = blockIdx.x * blockDim.x + threadIdx.x;
    if (e < NE) rank[e] = atomicAdd(&counts[ei[NE + e]], 1);
}

// block partial sums: 49 blocks x 256 threads x 8 elements
__global__ void k_s1(const int* __restrict__ counts, int* __restrict__ bsum) {
    __shared__ int sd[256];
    int tid = threadIdx.x, b = blockIdx.x;
    int base = b * 2048 + tid * 8;
    int s = 0;
    #pragma unroll
    for (int j = 0; j < 8; ++j) {
        int g = base + j;
        s += (g < NN) ? counts[g] : 0;
    }
    sd[tid] = s;
    __syncthreads();
    for (int d = 128; d; d >>= 1) {
        if (tid < d) sd[tid] += sd[tid + d];
        __syncthreads();
    }
    if (tid == 0) bsum[b] = sd[0];
}

// scan of 49 block sums + wdot prep + rowptr[NN]
__global__ void k_s2(const int* __restrict__ bsum, int* __restrict__ boff,
                     int* __restrict__ rowptr,
                     const float* __restrict__ We1, const float* __restrict__ ae1,
                     const float* __restrict__ We2, const float* __restrict__ ae2,
                     float* __restrict__ wdot) {
    int t = threadIdx.x;
    if (t == 0) {
        int run = 0;
        for (int b = 0; b < 49; ++b) { boff[b] = run; run += bsum[b]; }
        rowptr[NN] = NE;
    }
    if (t >= 64 && t < 68) {
        int h = t - 64;
        float s = 0.f;
        for (int c = 0; c < 32; ++c) s += We1[h*32+c] * ae1[h*32+c];
        wdot[h] = s;
    } else if (t == 68) {
        float s = 0.f;
        for (int c = 0; c < 32; ++c) s += We2[c] * ae2[c];
        wdot[4] = s;
    }
}

// per-block exclusive scan -> rowptr
__global__ void k_s3(const int* __restrict__ counts, const int* __restrict__ boff,
                     int* __restrict__ rowptr) {
    __shared__ int sT[256];
    int tid = threadIdx.x, b = blockIdx.x;
    int base = b * 2048 + tid * 8;
    int c[8];
    int s = 0;
    #pragma unroll
    for (int j = 0; j < 8; ++j) {
        int g = base + j;
        c[j] = (g < NN) ? counts[g] : 0;
        s += c[j];
    }
    sT[tid] = s;
    __syncthreads();
    for (int d = 1; d < 256; d <<= 1) {
        int v = (tid >= d) ? sT[tid - d] : 0;
        __syncthreads();
        sT[tid] += v;
        __syncthreads();
    }
    int run = (tid ? sT[tid - 1] : 0) + boff[b];
    #pragma unroll
    for (int j = 0; j < 8; ++j) {
        int g = base + j;
        if (g < NN) rowptr[g] = run;
        run += c[j];
    }
}

// scatter edges (packed {src, e_norm}) into dst-sorted order; fused BN/log1p
__global__ void k_scatter(const int* __restrict__ ei, const float* __restrict__ ea,
                          const float* __restrict__ g, const float* __restrict__ b,
                          const float* __restrict__ m, const float* __restrict__ v,
                          const int* __restrict__ rowptr, const int* __restrict__ rank,
                          int2* __restrict__ edges) {
    int e = blockIdx.x * blockDim.x + threadIdx.x;
    if (e >= NE) return;
    int dst = ei[NE + e];
    int pos = rowptr[dst] + rank[e];
    float en = (log1pf(ea[e]) - m[0]) * rsqrtf(v[0] + 1e-5f) * g[0] + b[0];
    edges[pos] = make_int2(ei[e], __float_as_int(en));
}

// ---------- node transform L1: h1 = x@W1, W1 column in VGPRs ----------
__global__ void k1_node1(const float* __restrict__ x, const float* __restrict__ W1,
                         const float* __restrict__ as1, const float* __restrict__ ad1,
                         float* __restrict__ h1, float* __restrict__ as1n,
                         float* __restrict__ ad1n) {
    __shared__ float xs[4][64];
    int tid = threadIdx.x, wid = tid >> 6, lane = tid & 63;
    float wc0[64], wc1[64];
    #pragma unroll
    for (int k = 0; k < 64; ++k) {
        wc0[k] = W1[k*128 + lane];
        wc1[k] = W1[k*128 + 64 + lane];
    }
    float asc0 = as1[lane], asc1 = as1[64 + lane];
    float adc0 = ad1[lane], adc1 = ad1[64 + lane];
    int gw = (blockIdx.x << 2) + wid;
    int nw = gridDim.x << 2;
    for (int n = gw; n < NN; n += nw) {
        xs[wid][lane] = x[n*64 + lane];
        float a0 = 0.f, a1 = 0.f;
        #pragma unroll
        for (int k4 = 0; k4 < 16; ++k4) {
            float4 xq = *(const float4*)&xs[wid][k4*4];
            a0 = fmaf(xq.x, wc0[4*k4+0], a0); a1 = fmaf(xq.x, wc1[4*k4+0], a1);
            a0 = fmaf(xq.y, wc0[4*k4+1], a0); a1 = fmaf(xq.y, wc1[4*k4+1], a1);
            a0 = fmaf(xq.z, wc0[4*k4+2], a0); a1 = fmaf(xq.z, wc1[4*k4+2], a1);
            a0 = fmaf(xq.w, wc0[4*k4+3], a0); a1 = fmaf(xq.w, wc1[4*k4+3], a1);
        }
        h1[(size_t)n*128 + lane]      = a0;
        h1[(size_t)n*128 + 64 + lane] = a1;
        float p0 = a0*asc0, p1 = a1*asc1, q0 = a0*adc0, q1 = a1*adc1;
        #pragma unroll
        for (int d = 16; d; d >>= 1) {
            p0 += __shfl_xor(p0, d); p1 += __shfl_xor(p1, d);
            q0 += __shfl_xor(q0, d); q1 += __shfl_xor(q1, d);
        }
        if (lane == 0) {
            as1n[n*4+0] = p0; as1n[n*4+2] = p1;
            ad1n[n*4+0] = q0; ad1n[n*4+2] = q1;
        } else if (lane == 32) {
            as1n[n*4+1] = p0; as1n[n*4+3] = p1;
            ad1n[n*4+1] = q0; ad1n[n*4+3] = q1;
        }
    }
}

// ---------- L1 aggregate (no-max softmax) + epilogue + h@W2 ----------
__global__ void __launch_bounds__(256)
kA1(const int* __restrict__ rowptr, const int2* __restrict__ edges,
    const float* __restrict__ as1n, const float* __restrict__ ad1n,
    const float* __restrict__ wdot, const float* __restrict__ h1,
    const float* __restrict__ b1, const float* __restrict__ W2,
    const float* __restrict__ as2, const float* __restrict__ ad2,
    float* __restrict__ h2, float* __restrict__ as2n, float* __restrict__ ad2n) {
    __shared__ float W2s[128*32];
    __shared__ float slot[4][128];
    __shared__ float as2s[32], ad2s[32], b1s[128];
    int tid = threadIdx.x, wid = tid >> 6, lane = tid & 63;
    for (int i = tid; i < 4096; i += 256) W2s[i] = W2[i];
    if (tid < 32) { as2s[tid] = as2[tid]; ad2s[tid] = ad2[tid]; }
    if (tid < 128) b1s[tid] = b1[tid];
    __syncthreads();

    int n = blockIdx.x * 4 + wid;
    int row0 = rowptr[n], row1 = rowptr[n + 1];
    float4 wd  = *(const float4*)wdot;
    float4 adv = *(const float4*)&ad1n[n*4];
    int hc0 = lane >> 5;
    float den0 = 0.f, den1 = 0.f, den2 = 0.f, den3 = 0.f;
    float acc0 = 0.f, acc1 = 0.f;

    for (int base = row0; base < row1; base += 64) {
        int j = base + lane;
        bool val = j < row1;
        int2 ep = val ? edges[j] : make_int2(0, 0);
        int sv = ep.x;
        float ev = __int_as_float(ep.y);
        float4 asv = *(const float4*)&as1n[sv*4];
        float a0 = asv.x + adv.x + ev*wd.x; a0 = fmaxf(a0, 0.2f*a0);
        float a1 = asv.y + adv.y + ev*wd.y; a1 = fmaxf(a1, 0.2f*a1);
        float a2 = asv.z + adv.z + ev*wd.z; a2 = fmaxf(a2, 0.2f*a2);
        float a3 = asv.w + adv.w + ev*wd.w; a3 = fmaxf(a3, 0.2f*a3);
        float p0 = val ? __expf(a0) : 0.f; den0 += p0;
        float p1 = val ? __expf(a1) : 0.f; den1 += p1;
        float p2 = val ? __expf(a2) : 0.f; den2 += p2;
        float p3 = val ? __expf(a3) : 0.f; den3 += p3;

        int cnt = min(64, row1 - base);
        int i = 0;
        for (; i + 1 < cnt; i += 2) {
            int sA = __shfl(sv, i), sB = __shfl(sv, i+1);
            float A0 = __shfl(p0, i),   A1 = __shfl(p1, i);
            float A2 = __shfl(p2, i),   A3 = __shfl(p3, i);
            float B0 = __shfl(p0, i+1), B1 = __shfl(p1, i+1);
            float B2 = __shfl(p2, i+1), B3 = __shfl(p3, i+1);
            const float* hA = h1 + (size_t)sA * 128;
            const float* hB = h1 + (size_t)sB * 128;
            float hA0 = hA[lane], hA1 = hA[lane + 64];
            float hB0 = hB[lane], hB1 = hB[lane + 64];
            float eLoA = hc0 ? A1 : A0, eHiA = hc0 ? A3 : A2;
            float eLoB = hc0 ? B1 : B0, eHiB = hc0 ? B3 : B2;
            acc0 = fmaf(eLoA, hA0, acc0); acc1 = fmaf(eHiA, hA1, acc1);
            acc0 = fmaf(eLoB, hB0, acc0); acc1 = fmaf(eHiB, hB1, acc1);
        }
        if (i < cnt) {
            int sA = __shfl(sv, i);
            float A0 = __shfl(p0, i), A1 = __shfl(p1, i);
            float A2 = __shfl(p2, i), A3 = __shfl(p3, i);
            const float* hA = h1 + (size_t)sA * 128;
            float eLoA = hc0 ? A1 : A0, eHiA = hc0 ? A3 : A2;
            acc0 = fmaf(eLoA, hA[lane], acc0);
            acc1 = fmaf(eHiA, hA[lane + 64], acc1);
        }
    }
    #pragma unroll
    for (int d = 32; d; d >>= 1) {
        den0 += __shfl_xor(den0, d); den1 += __shfl_xor(den1, d);
        den2 += __shfl_xor(den2, d); den3 += __shfl_xor(den3, d);
    }
    float dLo = hc0 ? den1 : den0;
    float dHi = hc0 ? den3 : den2;
    float o0 = acc0 / (dLo + 1e-16f) + b1s[lane];
    float o1 = acc1 / (dHi + 1e-16f) + b1s[lane + 64];
    o0 = o0 > 0.f ? o0 : expm1f(o0);
    o1 = o1 > 0.f ? o1 : expm1f(o1);
    slot[wid][lane]      = o0;
    slot[wid][lane + 64] = o1;   // wave-local LDS, in-order

    // h2 = elu(out1) @ W2, k-split across wave halves
    int c = lane & 31, k0 = (lane >> 5) * 64;
    float s2 = 0.f;
    #pragma unroll
    for (int k = 0; k < 64; ++k)
        s2 = fmaf(slot[wid][k0 + k], W2s[(k0 + k)*32 + c], s2);
    s2 += __shfl_xor(s2, 32);
    if (lane < 32) h2[(size_t)n*32 + c] = s2;
    float av = s2 * as2s[c] * 0.5f;
    float dv = s2 * ad2s[c] * 0.5f;
    #pragma unroll
    for (int d = 32; d; d >>= 1) { av += __shfl_xor(av, d); dv += __shfl_xor(dv, d); }
    if (lane == 0) { as2n[n] = av; ad2n[n] = dv; }
}

// ---------- L2 aggregate (no-max) + z + decoder MLP ----------
__global__ void __launch_bounds__(256)
kA2(const int* __restrict__ rowptr, const int2* __restrict__ edges,
    const float* __restrict__ as2n, const float* __restrict__ ad2n,
    const float* __restrict__ wdot, const float* __restrict__ h2,
    const float* __restrict__ b2, const float* __restrict__ Wd1,
    const float* __restrict__ bd1, const float* __restrict__ Wd2,
    const float* __restrict__ bd2, float* __restrict__ out) {
    __shared__ float Wd1s[32*32], Wd2s[32*64];
    __shared__ float zs[4][32], ts[4][32];
    __shared__ float b2s[32], bd1s[32], bd2s[64];
    int tid = threadIdx.x, wid = tid >> 6, lane = tid & 63;
    int half = lane >> 5, l5 = lane & 31;
    for (int i = tid; i < 1024; i += 256) Wd1s[i] = Wd1[i];
    for (int i = tid; i < 2048; i += 256) Wd2s[i] = Wd2[i];
    if (tid < 32) { b2s[tid] = b2[tid]; bd1s[tid] = bd1[tid]; }
    if (tid < 64) bd2s[tid] = bd2[tid];
    __syncthreads();

    int n = blockIdx.x * 4 + wid;
    int row0 = rowptr[n], row1 = rowptr[n + 1];
    float wd4 = wdot[4];
    float adn = ad2n[n];
    float den = 0.f, acc = 0.f;

    for (int base = row0; base < row1; base += 64) {
        int j = base + lane;
        bool val = j < row1;
        int2 ep = val ? edges[j] : make_int2(0, 0);
        int sv = ep.x;
        float ev = __int_as_float(ep.y);
        float a = as2n[sv] + adn + ev * wd4;
        a = fmaxf(a, 0.2f*a);
        float p = val ? __expf(a) : 0.f;
        den += p;

        int cnt = min(64, row1 - base);
        int t = 0;
        for (; 2*t + 1 < cnt; ++t) {
            int sA = __shfl(sv, 2*t), sB = __shfl(sv, 2*t + 1);
            float eA = __shfl(p, 2*t), eB = __shfl(p, 2*t + 1);
            int s = half ? sB : sA;
            float ex = half ? eB : eA;
            acc = fmaf(ex, h2[(size_t)s*32 + l5], acc);
        }
        if (2*t < cnt) {
            int sA = __shfl(sv, 2*t);
            float eA = __shfl(p, 2*t);
            if (!half) acc = fmaf(eA, h2[(size_t)sA*32 + l5], acc);
        }
    }
    #pragma unroll
    for (int d = 32; d; d >>= 1) den += __shfl_xor(den, d);
    acc += __shfl_xor(acc, 32);
    float z = acc / (den + 1e-16f) + b2s[l5];
    if (lane < 32) {
        out[(size_t)n*32 + l5] = z;
        zs[wid][l5] = z;
    }
    // decoder: t = elu(z@Wd1+bd1); x_hat = t@Wd2+bd2
    int kk0 = half * 16;
    float t2 = 0.f;
    #pragma unroll
    for (int k = 0; k < 16; ++k)
        t2 = fmaf(zs[wid][kk0 + k], Wd1s[(kk0 + k)*32 + l5], t2);
    t2 += __shfl_xor(t2, 32);
    t2 += bd1s[l5];
    t2 = t2 > 0.f ? t2 : expm1f(t2);
    if (lane < 32) ts[wid][l5] = t2;

    float xo = bd2s[lane];
    #pragma unroll
    for (int k = 0; k < 32; ++k)
        xo = fmaf(ts[wid][k], Wd2s[k*64 + lane], xo);
    out[(size_t)NN*32 + (size_t)n*64 + lane] = xo;
}

extern "C" void kernel_launch(void* const* d_in, const int* in_sizes, int n_in,
                              void* d_out, int out_size, void* d_ws, size_t ws_size,
                              hipStream_t stream) {
    const float* x    = (const float*)d_in[0];
    const int*   ei   = (const int*)  d_in[1];
    const float* ea   = (const float*)d_in[2];
    const float* bng  = (const float*)d_in[3];
    const float* bnb  = (const float*)d_in[4];
    const float* bnm  = (const float*)d_in[5];
    const float* bnv  = (const float*)d_in[6];
    const float* W1   = (const float*)d_in[7];
    const float* as1  = (const float*)d_in[8];
    const float* ad1  = (const float*)d_in[9];
    const float* We1  = (const float*)d_in[10];
    const float* ae1  = (const float*)d_in[11];
    const float* b1   = (const float*)d_in[12];
    const float* W2   = (const float*)d_in[13];
    const float* as2  = (const float*)d_in[14];
    const float* ad2  = (const float*)d_in[15];
    const float* We2  = (const float*)d_in[16];
    const float* ae2  = (const float*)d_in[17];
    const float* b2   = (const float*)d_in[18];
    const float* Wd1  = (const float*)d_in[19];
    const float* bd1  = (const float*)d_in[20];
    const float* Wd2  = (const float*)d_in[21];
    const float* bd2  = (const float*)d_in[22];
    float* out = (float*)d_out;

    float* wsf   = (float*)d_ws;
    float* h1    = wsf;                        // NN*128
    float* as1n  = h1    + (size_t)NN*128;     // NN*4
    float* ad1n  = as1n  + (size_t)NN*4;       // NN*4
    float* h2    = ad1n  + (size_t)NN*4;       // NN*32
    float* as2n  = h2    + (size_t)NN*32;      // NN
    float* ad2n  = as2n  + NN;                 // NN
    float* wdot  = ad2n  + NN;                 // 8
    int2*  edges = (int2*)(wdot + 8);          // NE int2 (8B-aligned)
    int*   rank  = (int*)(edges + NE);         // NE
    int*   counts = rank + NE;                 // NN
    int*   rowptr = counts + NN;               // NN+1
    int*   bsum   = rowptr + NN + 1;           // 64
    int*   boff   = bsum + 64;                 // 64

    hipMemsetAsync(counts, 0, NN * sizeof(int), stream);
    hipLaunchKernelGGL(k_hist, dim3((NE+255)/256), dim3(256), 0, stream, ei, counts, rank);
    hipLaunchKernelGGL(k_s1, dim3(49), dim3(256), 0, stream, counts, bsum);
    hipLaunchKernelGGL(k_s2, dim3(1), dim3(128), 0, stream,
                       bsum, boff, rowptr, We1, ae1, We2, ae2, wdot);
    hipLaunchKernelGGL(k_s3, dim3(49), dim3(256), 0, stream, counts, boff, rowptr);
    hipLaunchKernelGGL(k_scatter, dim3((NE+255)/256), dim3(256), 0, stream,
                       ei, ea, bng, bnb, bnm, bnv, rowptr, rank, edges);
    hipLaunchKernelGGL(k1_node1, dim3(1024), dim3(256), 0, stream,
                       x, W1, as1, ad1, h1, as1n, ad1n);
    hipLaunchKernelGGL(kA1, dim3(NN/4), dim3(256), 0, stream,
                       rowptr, edges, as1n, ad1n, wdot, h1, b1, W2, as2, ad2,
                       h2, as2n, ad2n);
    hipLaunchKernelGGL(kA2, dim3(NN/4), dim3(256), 0, stream,
                       rowptr, edges, as2n, ad2n, wdot, h2, b2, Wd1, bd1, Wd2, bd2,
                       out);
}

// Round 4
// 480.188 us; speedup vs baseline: 3.5140x; 1.2788x over previous
//
#include <hip/hip_runtime.h>
#include <math.h>

#define NN 100000
#define NE 1600000

// ---------- CSR build: hist with rank recording ----------
__global__ void k_hist(const int* __restrict__ ei, int* __restrict__ counts,
                       int* __restrict__ rank) {
    int e = blockIdx.x * blockDim.x + threadIdx.x;
    if (e < NE) rank[e] = atomicAdd(&counts[ei[NE + e]], 1);
}

// block partial sums: 49 blocks x 256 threads x 8 elements
__global__ void k_s1(const int* __restrict__ counts, int* __restrict__ bsum) {
    __shared__ int sd[256];
    int tid = threadIdx.x, b = blockIdx.x;
    int base = b * 2048 + tid * 8;
    int s = 0;
    #pragma unroll
    for (int j = 0; j < 8; ++j) {
        int g = base + j;
        s += (g < NN) ? counts[g] : 0;
    }
    sd[tid] = s;
    __syncthreads();
    for (int d = 128; d; d >>= 1) {
        if (tid < d) sd[tid] += sd[tid + d];
        __syncthreads();
    }
    if (tid == 0) bsum[b] = sd[0];
}

// scan of 49 block sums + wdot prep + rowptr[NN]
__global__ void k_s2(const int* __restrict__ bsum, int* __restrict__ boff,
                     int* __restrict__ rowptr,
                     const float* __restrict__ We1, const float* __restrict__ ae1,
                     const float* __restrict__ We2, const float* __restrict__ ae2,
                     float* __restrict__ wdot) {
    int t = threadIdx.x;
    if (t == 0) {
        int run = 0;
        for (int b = 0; b < 49; ++b) { boff[b] = run; run += bsum[b]; }
        rowptr[NN] = NE;
    }
    if (t >= 64 && t < 68) {
        int h = t - 64;
        float s = 0.f;
        for (int c = 0; c < 32; ++c) s += We1[h*32+c] * ae1[h*32+c];
        wdot[h] = s;
    } else if (t == 68) {
        float s = 0.f;
        for (int c = 0; c < 32; ++c) s += We2[c] * ae2[c];
        wdot[4] = s;
    }
}

// per-block exclusive scan -> rowptr
__global__ void k_s3(const int* __restrict__ counts, const int* __restrict__ boff,
                     int* __restrict__ rowptr) {
    __shared__ int sT[256];
    int tid = threadIdx.x, b = blockIdx.x;
    int base = b * 2048 + tid * 8;
    int c[8];
    int s = 0;
    #pragma unroll
    for (int j = 0; j < 8; ++j) {
        int g = base + j;
        c[j] = (g < NN) ? counts[g] : 0;
        s += c[j];
    }
    sT[tid] = s;
    __syncthreads();
    for (int d = 1; d < 256; d <<= 1) {
        int v = (tid >= d) ? sT[tid - d] : 0;
        __syncthreads();
        sT[tid] += v;
        __syncthreads();
    }
    int run = (tid ? sT[tid - 1] : 0) + boff[b];
    #pragma unroll
    for (int j = 0; j < 8; ++j) {
        int g = base + j;
        if (g < NN) rowptr[g] = run;
        run += c[j];
    }
}

// scatter edges (packed {src, e_norm}) into dst-sorted order; fused BN/log1p
__global__ void k_scatter(const int* __restrict__ ei, const float* __restrict__ ea,
                          const float* __restrict__ g, const float* __restrict__ b,
                          const float* __restrict__ m, const float* __restrict__ v,
                          const int* __restrict__ rowptr, const int* __restrict__ rank,
                          int2* __restrict__ edges) {
    int e = blockIdx.x * blockDim.x + threadIdx.x;
    if (e >= NE) return;
    int dst = ei[NE + e];
    int pos = rowptr[dst] + rank[e];
    float en = (log1pf(ea[e]) - m[0]) * rsqrtf(v[0] + 1e-5f) * g[0] + b[0];
    edges[pos] = make_int2(ei[e], __float_as_int(en));
}

// ---------- node transform L1: W1 columns in VGPRs, x row via scalar loads ----------
// __launch_bounds__(256,2): VGPR cap 256 so the 128 W1 registers stay resident
// (R3 regression: default heuristic capped at 64 VGPR -> 33MB scratch spill).
__global__ void __launch_bounds__(256, 2)
k1_node1(const float* __restrict__ x, const float* __restrict__ W1,
         const float* __restrict__ as1, const float* __restrict__ ad1,
         float* __restrict__ h1, float* __restrict__ as1n,
         float* __restrict__ ad1n) {
    int tid = threadIdx.x, wid = tid >> 6, lane = tid & 63;
    float wc0[64], wc1[64];
    #pragma unroll
    for (int k = 0; k < 64; ++k) {
        wc0[k] = W1[k*128 + lane];
        wc1[k] = W1[k*128 + 64 + lane];
    }
    float asc0 = as1[lane], asc1 = as1[64 + lane];
    float adc0 = ad1[lane], adc1 = ad1[64 + lane];
    int gw = (blockIdx.x << 2) + wid;
    int nw = gridDim.x << 2;
    for (int n = gw; n < NN; n += nw) {
        // wave-uniform node index -> SGPR -> x row reads become s_load (no LDS)
        int nu = __builtin_amdgcn_readfirstlane(n);
        const float* xr = x + (size_t)nu * 64;
        float a0 = 0.f, a1 = 0.f;
        #pragma unroll
        for (int k = 0; k < 64; ++k) {
            float xk = xr[k];
            a0 = fmaf(xk, wc0[k], a0);
            a1 = fmaf(xk, wc1[k], a1);
        }
        h1[(size_t)nu*128 + lane]      = a0;
        h1[(size_t)nu*128 + 64 + lane] = a1;
        float p0 = a0*asc0, p1 = a1*asc1, q0 = a0*adc0, q1 = a1*adc1;
        #pragma unroll
        for (int d = 16; d; d >>= 1) {
            p0 += __shfl_xor(p0, d); p1 += __shfl_xor(p1, d);
            q0 += __shfl_xor(q0, d); q1 += __shfl_xor(q1, d);
        }
        if (lane == 0) {
            as1n[nu*4+0] = p0; as1n[nu*4+2] = p1;
            ad1n[nu*4+0] = q0; ad1n[nu*4+2] = q1;
        } else if (lane == 32) {
            as1n[nu*4+1] = p0; as1n[nu*4+3] = p1;
            ad1n[nu*4+1] = q0; ad1n[nu*4+3] = q1;
        }
    }
}

// ---------- L1 aggregate (no-max softmax) + epilogue + h@W2 ----------
__global__ void __launch_bounds__(256)
kA1(const int* __restrict__ rowptr, const int2* __restrict__ edges,
    const float* __restrict__ as1n, const float* __restrict__ ad1n,
    const float* __restrict__ wdot, const float* __restrict__ h1,
    const float* __restrict__ b1, const float* __restrict__ W2,
    const float* __restrict__ as2, const float* __restrict__ ad2,
    float* __restrict__ h2, float* __restrict__ as2n, float* __restrict__ ad2n) {
    __shared__ float W2s[128*32];
    __shared__ float slot[4][128];
    __shared__ float as2s[32], ad2s[32], b1s[128];
    int tid = threadIdx.x, wid = tid >> 6, lane = tid & 63;
    for (int i = tid; i < 4096; i += 256) W2s[i] = W2[i];
    if (tid < 32) { as2s[tid] = as2[tid]; ad2s[tid] = ad2[tid]; }
    if (tid < 128) b1s[tid] = b1[tid];
    __syncthreads();

    int n = blockIdx.x * 4 + wid;
    int row0 = rowptr[n], row1 = rowptr[n + 1];
    float4 wd  = *(const float4*)wdot;
    float4 adv = *(const float4*)&ad1n[n*4];
    int hc0 = lane >> 5;
    float den0 = 0.f, den1 = 0.f, den2 = 0.f, den3 = 0.f;
    float acc0 = 0.f, acc1 = 0.f;

    for (int base = row0; base < row1; base += 64) {
        int j = base + lane;
        bool val = j < row1;
        int2 ep = val ? edges[j] : make_int2(0, 0);
        int sv = ep.x;
        float ev = __int_as_float(ep.y);
        float4 asv = *(const float4*)&as1n[sv*4];
        float a0 = asv.x + adv.x + ev*wd.x; a0 = fmaxf(a0, 0.2f*a0);
        float a1 = asv.y + adv.y + ev*wd.y; a1 = fmaxf(a1, 0.2f*a1);
        float a2 = asv.z + adv.z + ev*wd.z; a2 = fmaxf(a2, 0.2f*a2);
        float a3 = asv.w + adv.w + ev*wd.w; a3 = fmaxf(a3, 0.2f*a3);
        float p0 = val ? __expf(a0) : 0.f; den0 += p0;
        float p1 = val ? __expf(a1) : 0.f; den1 += p1;
        float p2 = val ? __expf(a2) : 0.f; den2 += p2;
        float p3 = val ? __expf(a3) : 0.f; den3 += p3;

        int cnt = min(64, row1 - base);
        int i = 0;
        for (; i + 1 < cnt; i += 2) {
            int sA = __shfl(sv, i), sB = __shfl(sv, i+1);
            float A0 = __shfl(p0, i),   A1 = __shfl(p1, i);
            float A2 = __shfl(p2, i),   A3 = __shfl(p3, i);
            float B0 = __shfl(p0, i+1), B1 = __shfl(p1, i+1);
            float B2 = __shfl(p2, i+1), B3 = __shfl(p3, i+1);
            const float* hA = h1 + (size_t)sA * 128;
            const float* hB = h1 + (size_t)sB * 128;
            float hA0 = hA[lane], hA1 = hA[lane + 64];
            float hB0 = hB[lane], hB1 = hB[lane + 64];
            float eLoA = hc0 ? A1 : A0, eHiA = hc0 ? A3 : A2;
            float eLoB = hc0 ? B1 : B0, eHiB = hc0 ? B3 : B2;
            acc0 = fmaf(eLoA, hA0, acc0); acc1 = fmaf(eHiA, hA1, acc1);
            acc0 = fmaf(eLoB, hB0, acc0); acc1 = fmaf(eHiB, hB1, acc1);
        }
        if (i < cnt) {
            int sA = __shfl(sv, i);
            float A0 = __shfl(p0, i), A1 = __shfl(p1, i);
            float A2 = __shfl(p2, i), A3 = __shfl(p3, i);
            const float* hA = h1 + (size_t)sA * 128;
            float eLoA = hc0 ? A1 : A0, eHiA = hc0 ? A3 : A2;
            acc0 = fmaf(eLoA, hA[lane], acc0);
            acc1 = fmaf(eHiA, hA[lane + 64], acc1);
        }
    }
    #pragma unroll
    for (int d = 32; d; d >>= 1) {
        den0 += __shfl_xor(den0, d); den1 += __shfl_xor(den1, d);
        den2 += __shfl_xor(den2, d); den3 += __shfl_xor(den3, d);
    }
    float dLo = hc0 ? den1 : den0;
    float dHi = hc0 ? den3 : den2;
    float o0 = acc0 / (dLo + 1e-16f) + b1s[lane];
    float o1 = acc1 / (dHi + 1e-16f) + b1s[lane + 64];
    o0 = o0 > 0.f ? o0 : expm1f(o0);
    o1 = o1 > 0.f ? o1 : expm1f(o1);
    slot[wid][lane]      = o0;
    slot[wid][lane + 64] = o1;   // wave-local LDS, in-order

    // h2 = elu(out1) @ W2, k-split across wave halves
    int c = lane & 31, k0 = (lane >> 5) * 64;
    float s2 = 0.f;
    #pragma unroll
    for (int k = 0; k < 64; ++k)
        s2 = fmaf(slot[wid][k0 + k], W2s[(k0 + k)*32 + c], s2);
    s2 += __shfl_xor(s2, 32);
    if (lane < 32) h2[(size_t)n*32 + c] = s2;
    float av = s2 * as2s[c] * 0.5f;
    float dv = s2 * ad2s[c] * 0.5f;
    #pragma unroll
    for (int d = 32; d; d >>= 1) { av += __shfl_xor(av, d); dv += __shfl_xor(dv, d); }
    if (lane == 0) { as2n[n] = av; ad2n[n] = dv; }
}

// ---------- L2 aggregate (no-max) + z + decoder MLP ----------
__global__ void __launch_bounds__(256)
kA2(const int* __restrict__ rowptr, const int2* __restrict__ edges,
    const float* __restrict__ as2n, const float* __restrict__ ad2n,
    const float* __restrict__ wdot, const float* __restrict__ h2,
    const float* __restrict__ b2, const float* __restrict__ Wd1,
    const float* __restrict__ bd1, const float* __restrict__ Wd2,
    const float* __restrict__ bd2, float* __restrict__ out) {
    __shared__ float Wd1s[32*32], Wd2s[32*64];
    __shared__ float zs[4][32], ts[4][32];
    __shared__ float b2s[32], bd1s[32], bd2s[64];
    int tid = threadIdx.x, wid = tid >> 6, lane = tid & 63;
    int half = lane >> 5, l5 = lane & 31;
    for (int i = tid; i < 1024; i += 256) Wd1s[i] = Wd1[i];
    for (int i = tid; i < 2048; i += 256) Wd2s[i] = Wd2[i];
    if (tid < 32) { b2s[tid] = b2[tid]; bd1s[tid] = bd1[tid]; }
    if (tid < 64) bd2s[tid] = bd2[tid];
    __syncthreads();

    int n = blockIdx.x * 4 + wid;
    int row0 = rowptr[n], row1 = rowptr[n + 1];
    float wd4 = wdot[4];
    float adn = ad2n[n];
    float den = 0.f, acc = 0.f;

    for (int base = row0; base < row1; base += 64) {
        int j = base + lane;
        bool val = j < row1;
        int2 ep = val ? edges[j] : make_int2(0, 0);
        int sv = ep.x;
        float ev = __int_as_float(ep.y);
        float a = as2n[sv] + adn + ev * wd4;
        a = fmaxf(a, 0.2f*a);
        float p = val ? __expf(a) : 0.f;
        den += p;

        int cnt = min(64, row1 - base);
        int t = 0;
        for (; 2*t + 1 < cnt; ++t) {
            int sA = __shfl(sv, 2*t), sB = __shfl(sv, 2*t + 1);
            float eA = __shfl(p, 2*t), eB = __shfl(p, 2*t + 1);
            int s = half ? sB : sA;
            float ex = half ? eB : eA;
            acc = fmaf(ex, h2[(size_t)s*32 + l5], acc);
        }
        if (2*t < cnt) {
            int sA = __shfl(sv, 2*t);
            float eA = __shfl(p, 2*t);
            if (!half) acc = fmaf(eA, h2[(size_t)sA*32 + l5], acc);
        }
    }
    #pragma unroll
    for (int d = 32; d; d >>= 1) den += __shfl_xor(den, d);
    acc += __shfl_xor(acc, 32);
    float z = acc / (den + 1e-16f) + b2s[l5];
    if (lane < 32) {
        out[(size_t)n*32 + l5] = z;
        zs[wid][l5] = z;
    }
    // decoder: t = elu(z@Wd1+bd1); x_hat = t@Wd2+bd2
    int kk0 = half * 16;
    float t2 = 0.f;
    #pragma unroll
    for (int k = 0; k < 16; ++k)
        t2 = fmaf(zs[wid][kk0 + k], Wd1s[(kk0 + k)*32 + l5], t2);
    t2 += __shfl_xor(t2, 32);
    t2 += bd1s[l5];
    t2 = t2 > 0.f ? t2 : expm1f(t2);
    if (lane < 32) ts[wid][l5] = t2;

    float xo = bd2s[lane];
    #pragma unroll
    for (int k = 0; k < 32; ++k)
        xo = fmaf(ts[wid][k], Wd2s[k*64 + lane], xo);
    out[(size_t)NN*32 + (size_t)n*64 + lane] = xo;
}

extern "C" void kernel_launch(void* const* d_in, const int* in_sizes, int n_in,
                              void* d_out, int out_size, void* d_ws, size_t ws_size,
                              hipStream_t stream) {
    const float* x    = (const float*)d_in[0];
    const int*   ei   = (const int*)  d_in[1];
    const float* ea   = (const float*)d_in[2];
    const float* bng  = (const float*)d_in[3];
    const float* bnb  = (const float*)d_in[4];
    const float* bnm  = (const float*)d_in[5];
    const float* bnv  = (const float*)d_in[6];
    const float* W1   = (const float*)d_in[7];
    const float* as1  = (const float*)d_in[8];
    const float* ad1  = (const float*)d_in[9];
    const float* We1  = (const float*)d_in[10];
    const float* ae1  = (const float*)d_in[11];
    const float* b1   = (const float*)d_in[12];
    const float* W2   = (const float*)d_in[13];
    const float* as2  = (const float*)d_in[14];
    const float* ad2  = (const float*)d_in[15];
    const float* We2  = (const float*)d_in[16];
    const float* ae2  = (const float*)d_in[17];
    const float* b2   = (const float*)d_in[18];
    const float* Wd1  = (const float*)d_in[19];
    const float* bd1  = (const float*)d_in[20];
    const float* Wd2  = (const float*)d_in[21];
    const float* bd2  = (const float*)d_in[22];
    float* out = (float*)d_out;

    float* wsf   = (float*)d_ws;
    float* h1    = wsf;                        // NN*128
    float* as1n  = h1    + (size_t)NN*128;     // NN*4
    float* ad1n  = as1n  + (size_t)NN*4;       // NN*4
    float* h2    = ad1n  + (size_t)NN*4;       // NN*32
    float* as2n  = h2    + (size_t)NN*32;      // NN
    float* ad2n  = as2n  + NN;                 // NN
    float* wdot  = ad2n  + NN;                 // 8
    int2*  edges = (int2*)(wdot + 8);          // NE int2 (8B-aligned)
    int*   rank  = (int*)(edges + NE);         // NE
    int*   counts = rank + NE;                 // NN
    int*   rowptr = counts + NN;               // NN+1
    int*   bsum   = rowptr + NN + 1;           // 64
    int*   boff   = bsum + 64;                 // 64

    hipMemsetAsync(counts, 0, NN * sizeof(int), stream);
    hipLaunchKernelGGL(k_hist, dim3((NE+255)/256), dim3(256), 0, stream, ei, counts, rank);
    hipLaunchKernelGGL(k_s1, dim3(49), dim3(256), 0, stream, counts, bsum);
    hipLaunchKernelGGL(k_s2, dim3(1), dim3(128), 0, stream,
                       bsum, boff, rowptr, We1, ae1, We2, ae2, wdot);
    hipLaunchKernelGGL(k_s3, dim3(49), dim3(256), 0, stream, counts, boff, rowptr);
    hipLaunchKernelGGL(k_scatter, dim3((NE+255)/256), dim3(256), 0, stream,
                       ei, ea, bng, bnb, bnm, bnv, rowptr, rank, edges);
    hipLaunchKernelGGL(k1_node1, dim3(1024), dim3(256), 0, stream,
                       x, W1, as1, ad1, h1, as1n, ad1n);
    hipLaunchKernelGGL(kA1, dim3(NN/4), dim3(256), 0, stream,
                       rowptr, edges, as1n, ad1n, wdot, h1, b1, W2, as2, ad2,
                       h2, as2n, ad2n);
    hipLaunchKernelGGL(kA2, dim3(NN/4), dim3(256), 0, stream,
                       rowptr, edges, as2n, ad2n, wdot, h2, b2, Wd1, bd1, Wd2, bd2,
                       out);
}

// Round 5
// 412.783 us; speedup vs baseline: 4.0878x; 1.1633x over previous
//
#include <hip/hip_runtime.h>
#include <hip/hip_fp16.h>
#include <math.h>

#define NN 100000
#define NE 1600000

// ---------- CSR build: hist with rank recording ----------
__global__ void k_hist(const int* __restrict__ ei, int* __restrict__ counts,
                       int* __restrict__ rank) {
    int e = blockIdx.x * blockDim.x + threadIdx.x;
    if (e < NE) rank[e] = atomicAdd(&counts[ei[NE + e]], 1);
}

__global__ void k_s1(const int* __restrict__ counts, int* __restrict__ bsum) {
    __shared__ int sd[256];
    int tid = threadIdx.x, b = blockIdx.x;
    int base = b * 2048 + tid * 8;
    int s = 0;
    #pragma unroll
    for (int j = 0; j < 8; ++j) {
        int g = base + j;
        s += (g < NN) ? counts[g] : 0;
    }
    sd[tid] = s;
    __syncthreads();
    for (int d = 128; d; d >>= 1) {
        if (tid < d) sd[tid] += sd[tid + d];
        __syncthreads();
    }
    if (tid == 0) bsum[b] = sd[0];
}

__global__ void k_s2(const int* __restrict__ bsum, int* __restrict__ boff,
                     int* __restrict__ rowptr,
                     const float* __restrict__ We1, const float* __restrict__ ae1,
                     const float* __restrict__ We2, const float* __restrict__ ae2,
                     float* __restrict__ wdot) {
    int t = threadIdx.x;
    if (t == 0) {
        int run = 0;
        for (int b = 0; b < 49; ++b) { boff[b] = run; run += bsum[b]; }
        rowptr[NN] = NE;
    }
    if (t >= 64 && t < 68) {
        int h = t - 64;
        float s = 0.f;
        for (int c = 0; c < 32; ++c) s += We1[h*32+c] * ae1[h*32+c];
        wdot[h] = s;
    } else if (t == 68) {
        float s = 0.f;
        for (int c = 0; c < 32; ++c) s += We2[c] * ae2[c];
        wdot[4] = s;
    }
}

__global__ void k_s3(const int* __restrict__ counts, const int* __restrict__ boff,
                     int* __restrict__ rowptr) {
    __shared__ int sT[256];
    int tid = threadIdx.x, b = blockIdx.x;
    int base = b * 2048 + tid * 8;
    int c[8];
    int s = 0;
    #pragma unroll
    for (int j = 0; j < 8; ++j) {
        int g = base + j;
        c[j] = (g < NN) ? counts[g] : 0;
        s += c[j];
    }
    sT[tid] = s;
    __syncthreads();
    for (int d = 1; d < 256; d <<= 1) {
        int v = (tid >= d) ? sT[tid - d] : 0;
        __syncthreads();
        sT[tid] += v;
        __syncthreads();
    }
    int run = (tid ? sT[tid - 1] : 0) + boff[b];
    #pragma unroll
    for (int j = 0; j < 8; ++j) {
        int g = base + j;
        if (g < NN) rowptr[g] = run;
        run += c[j];
    }
}

__global__ void k_scatter(const int* __restrict__ ei, const float* __restrict__ ea,
                          const float* __restrict__ g, const float* __restrict__ b,
                          const float* __restrict__ m, const float* __restrict__ v,
                          const int* __restrict__ rowptr, const int* __restrict__ rank,
                          int2* __restrict__ edges) {
    int e = blockIdx.x * blockDim.x + threadIdx.x;
    if (e >= NE) return;
    int dst = ei[NE + e];
    int pos = rowptr[dst] + rank[e];
    float en = (log1pf(ea[e]) - m[0]) * rsqrtf(v[0] + 1e-5f) * g[0] + b[0];
    edges[pos] = make_int2(ei[e], __float_as_int(en));
}

// ---------- node transform L1: channel-pair layout, h1 packed fp16 ----------
// lane covers channels (2*lane, 2*lane+1); head = lane>>4.
__global__ void __launch_bounds__(256, 2)
k1_node1(const float* __restrict__ x, const float* __restrict__ W1,
         const float* __restrict__ as1, const float* __restrict__ ad1,
         __half2* __restrict__ h1h, float* __restrict__ as1n,
         float* __restrict__ ad1n) {
    int tid = threadIdx.x, wid = tid >> 6, lane = tid & 63;
    float wc0[64], wc1[64];
    #pragma unroll
    for (int k = 0; k < 64; ++k) {
        wc0[k] = W1[k*128 + 2*lane];
        wc1[k] = W1[k*128 + 2*lane + 1];
    }
    float asc0 = as1[2*lane], asc1 = as1[2*lane+1];
    float adc0 = ad1[2*lane], adc1 = ad1[2*lane+1];
    int gw = (blockIdx.x << 2) + wid;
    int nw = gridDim.x << 2;
    for (int n = gw; n < NN; n += nw) {
        int nu = __builtin_amdgcn_readfirstlane(n);
        const float* xr = x + (size_t)nu * 64;
        float a0 = 0.f, a1 = 0.f;
        #pragma unroll
        for (int k = 0; k < 64; ++k) {
            float xk = xr[k];
            a0 = fmaf(xk, wc0[k], a0);
            a1 = fmaf(xk, wc1[k], a1);
        }
        h1h[(size_t)nu*64 + lane] = __float22half2_rn(make_float2(a0, a1));
        // per-head alpha partials: reduce within 16-lane group (one head each)
        float p = a0*asc0 + a1*asc1;
        float q = a0*adc0 + a1*adc1;
        #pragma unroll
        for (int d = 1; d < 16; d <<= 1) {
            p += __shfl_xor(p, d);
            q += __shfl_xor(q, d);
        }
        if ((lane & 15) == 0) {
            int h = lane >> 4;
            as1n[nu*4 + h] = p;
            ad1n[nu*4 + h] = q;
        }
    }
}

// ---------- L1 aggregate (no-max softmax, fp16 gather) + epilogue + h@W2 ----------
__global__ void __launch_bounds__(256)
kA1(const int* __restrict__ rowptr, const int2* __restrict__ edges,
    const float* __restrict__ as1n, const float* __restrict__ ad1n,
    const float* __restrict__ wdot, const __half2* __restrict__ h1h,
    const float* __restrict__ b1, const float* __restrict__ W2,
    const float* __restrict__ as2, const float* __restrict__ ad2,
    __half2* __restrict__ h2h, float* __restrict__ as2n, float* __restrict__ ad2n) {
    __shared__ float W2s[128*32];
    __shared__ float4 exs4[4][64];
    __shared__ int    srcl[4][64];
    __shared__ float  slot[4][128];
    int tid = threadIdx.x, wid = tid >> 6, lane = tid & 63;
    for (int i = tid; i < 4096; i += 256) W2s[i] = W2[i];
    __syncthreads();

    int n = blockIdx.x * 4 + wid;
    int row0 = rowptr[n], row1 = rowptr[n + 1];
    float4 wd  = *(const float4*)wdot;
    float4 adv = *(const float4*)&ad1n[n*4];
    int hc = lane >> 4;                  // head of this lane's channel pair
    float b1a = b1[2*lane], b1b = b1[2*lane+1];
    float den0 = 0.f, den1 = 0.f, den2 = 0.f, den3 = 0.f;
    float acc0 = 0.f, acc1 = 0.f;
    const float* exf = (const float*)&exs4[wid][0];

    for (int base = row0; base < row1; base += 64) {
        int j = base + lane;
        bool val = j < row1;
        int2 ep = val ? edges[j] : make_int2(0, 0);
        int sv = ep.x;
        float ev = __int_as_float(ep.y);
        float4 asv = *(const float4*)&as1n[sv*4];
        float a0 = asv.x + adv.x + ev*wd.x; a0 = fmaxf(a0, 0.2f*a0);
        float a1 = asv.y + adv.y + ev*wd.y; a1 = fmaxf(a1, 0.2f*a1);
        float a2 = asv.z + adv.z + ev*wd.z; a2 = fmaxf(a2, 0.2f*a2);
        float a3 = asv.w + adv.w + ev*wd.w; a3 = fmaxf(a3, 0.2f*a3);
        float p0 = val ? __expf(a0) : 0.f; den0 += p0;
        float p1 = val ? __expf(a1) : 0.f; den1 += p1;
        float p2 = val ? __expf(a2) : 0.f; den2 += p2;
        float p3 = val ? __expf(a3) : 0.f; den3 += p3;
        exs4[wid][lane] = make_float4(p0, p1, p2, p3);
        srcl[wid][lane] = sv;
        // same-wave LDS: in-order, no barrier needed

        int cnt = min(64, row1 - base);
        for (int i = 0; i < cnt; ++i) {
            int s = srcl[wid][i];                         // broadcast ds_read
            __half2 hv = h1h[(size_t)s*64 + lane];        // 1 dword: 2 channels
            float2 hf = __half22float2(hv);
            float ex = exf[i*4 + hc];                     // broadcast within group
            acc0 = fmaf(ex, hf.x, acc0);
            acc1 = fmaf(ex, hf.y, acc1);
        }
    }
    #pragma unroll
    for (int d = 32; d; d >>= 1) {
        den0 += __shfl_xor(den0, d); den1 += __shfl_xor(den1, d);
        den2 += __shfl_xor(den2, d); den3 += __shfl_xor(den3, d);
    }
    float dh = (hc == 0) ? den0 : (hc == 1) ? den1 : (hc == 2) ? den2 : den3;
    float r = 1.f / (dh + 1e-16f);
    float o0 = acc0 * r + b1a;
    float o1 = acc1 * r + b1b;
    o0 = o0 > 0.f ? o0 : expm1f(o0);
    o1 = o1 > 0.f ? o1 : expm1f(o1);
    *(float2*)&slot[wid][2*lane] = make_float2(o0, o1);

    // h2 = elu(out1) @ W2, k-split across wave halves
    int c = lane & 31, k0 = (lane >> 5) * 64;
    float s2 = 0.f;
    #pragma unroll
    for (int k = 0; k < 64; ++k)
        s2 = fmaf(slot[wid][k0 + k], W2s[(k0 + k)*32 + c], s2);
    s2 += __shfl_xor(s2, 32);
    int l4 = lane & 15;
    float za = __shfl(s2, 2*l4);
    float zb = __shfl(s2, 2*l4 + 1);
    if (lane < 16) h2h[(size_t)n*16 + l4] = __float22half2_rn(make_float2(za, zb));
    float av = s2 * as2[c] * 0.5f;   // each channel duplicated in both halves
    float dv = s2 * ad2[c] * 0.5f;
    #pragma unroll
    for (int d = 32; d; d >>= 1) { av += __shfl_xor(av, d); dv += __shfl_xor(dv, d); }
    if (lane == 0) { as2n[n] = av; ad2n[n] = dv; }
}

// ---------- L2 aggregate (fp16 gather, 4 edges/iter) + z + decoder MLP ----------
__global__ void __launch_bounds__(256)
kA2(const int* __restrict__ rowptr, const int2* __restrict__ edges,
    const float* __restrict__ as2n, const float* __restrict__ ad2n,
    const float* __restrict__ wdot, const __half2* __restrict__ h2h,
    const float* __restrict__ b2, const float* __restrict__ Wd1,
    const float* __restrict__ bd1, const float* __restrict__ Wd2,
    const float* __restrict__ bd2, float* __restrict__ out) {
    __shared__ float Wd1s[32*32], Wd2s[32*64];
    __shared__ float pl[4][64];
    __shared__ int   srcl[4][64];
    __shared__ float zs[4][32], ts[4][32];
    int tid = threadIdx.x, wid = tid >> 6, lane = tid & 63;
    int g = lane >> 4, l4 = lane & 15;
    int half = lane >> 5, l5 = lane & 31;
    for (int i = tid; i < 1024; i += 256) Wd1s[i] = Wd1[i];
    for (int i = tid; i < 2048; i += 256) Wd2s[i] = Wd2[i];
    __syncthreads();

    int n = blockIdx.x * 4 + wid;
    int row0 = rowptr[n], row1 = rowptr[n + 1];
    float wd4 = wdot[4];
    float adn = ad2n[n];
    float den = 0.f, acc0 = 0.f, acc1 = 0.f;

    for (int base = row0; base < row1; base += 64) {
        int j = base + lane;
        bool val = j < row1;
        int2 ep = val ? edges[j] : make_int2(0, 0);
        int sv = ep.x;
        float ev = __int_as_float(ep.y);
        float a = as2n[sv] + adn + ev * wd4;
        a = fmaxf(a, 0.2f*a);
        float p = val ? __expf(a) : 0.f;
        den += p;
        pl[wid][lane] = p;
        srcl[wid][lane] = sv;

        int cnt = min(64, row1 - base);
        for (int i = 0; i < cnt; i += 4) {
            int idx = i + g;
            bool ok = idx < cnt;
            int se   = ok ? srcl[wid][idx] : 0;
            float ex = ok ? pl[wid][idx] : 0.f;
            __half2 hv = h2h[(size_t)se*16 + l4];
            float2 hf = __half22float2(hv);
            acc0 = fmaf(ex, hf.x, acc0);
            acc1 = fmaf(ex, hf.y, acc1);
        }
    }
    #pragma unroll
    for (int d = 32; d; d >>= 1) den += __shfl_xor(den, d);
    acc0 += __shfl_xor(acc0, 16); acc0 += __shfl_xor(acc0, 32);
    acc1 += __shfl_xor(acc1, 16); acc1 += __shfl_xor(acc1, 32);
    float r = 1.f / (den + 1e-16f);
    if (lane < 16) {
        float z0 = acc0 * r + b2[2*l4];
        float z1 = acc1 * r + b2[2*l4 + 1];
        *(float2*)&out[(size_t)n*32 + 2*l4] = make_float2(z0, z1);
        *(float2*)&zs[wid][2*l4] = make_float2(z0, z1);
    }
    // decoder: t = elu(z@Wd1+bd1); x_hat = t@Wd2+bd2
    int kk0 = half * 16;
    float t2 = 0.f;
    #pragma unroll
    for (int k = 0; k < 16; ++k)
        t2 = fmaf(zs[wid][kk0 + k], Wd1s[(kk0 + k)*32 + l5], t2);
    t2 += __shfl_xor(t2, 32);
    t2 += bd1[l5];
    t2 = t2 > 0.f ? t2 : expm1f(t2);
    if (lane < 32) ts[wid][l5] = t2;

    float xo = bd2[lane];
    #pragma unroll
    for (int k = 0; k < 32; ++k)
        xo = fmaf(ts[wid][k], Wd2s[k*64 + lane], xo);
    out[(size_t)NN*32 + (size_t)n*64 + lane] = xo;
}

extern "C" void kernel_launch(void* const* d_in, const int* in_sizes, int n_in,
                              void* d_out, int out_size, void* d_ws, size_t ws_size,
                              hipStream_t stream) {
    const float* x    = (const float*)d_in[0];
    const int*   ei   = (const int*)  d_in[1];
    const float* ea   = (const float*)d_in[2];
    const float* bng  = (const float*)d_in[3];
    const float* bnb  = (const float*)d_in[4];
    const float* bnm  = (const float*)d_in[5];
    const float* bnv  = (const float*)d_in[6];
    const float* W1   = (const float*)d_in[7];
    const float* as1  = (const float*)d_in[8];
    const float* ad1  = (const float*)d_in[9];
    const float* We1  = (const float*)d_in[10];
    const float* ae1  = (const float*)d_in[11];
    const float* b1   = (const float*)d_in[12];
    const float* W2   = (const float*)d_in[13];
    const float* as2  = (const float*)d_in[14];
    const float* ad2  = (const float*)d_in[15];
    const float* We2  = (const float*)d_in[16];
    const float* ae2  = (const float*)d_in[17];
    const float* b2   = (const float*)d_in[18];
    const float* Wd1  = (const float*)d_in[19];
    const float* bd1  = (const float*)d_in[20];
    const float* Wd2  = (const float*)d_in[21];
    const float* bd2  = (const float*)d_in[22];
    float* out = (float*)d_out;

    float* wsf   = (float*)d_ws;
    __half2* h1h = (__half2*)wsf;                    // NN*64 (25.6MB)
    float* as1n  = (float*)(h1h + (size_t)NN*64);    // NN*4
    float* ad1n  = as1n + (size_t)NN*4;              // NN*4
    __half2* h2h = (__half2*)(ad1n + (size_t)NN*4);  // NN*16
    float* as2n  = (float*)(h2h + (size_t)NN*16);    // NN
    float* ad2n  = as2n + NN;                        // NN
    float* wdot  = ad2n + NN;                        // 8
    int2*  edges = (int2*)(wdot + 8);                // NE
    int*   rank  = (int*)(edges + NE);               // NE
    int*   counts = rank + NE;                       // NN
    int*   rowptr = counts + NN;                     // NN+1
    int*   bsum   = rowptr + NN + 1;                 // 64
    int*   boff   = bsum + 64;                       // 64

    hipMemsetAsync(counts, 0, NN * sizeof(int), stream);
    hipLaunchKernelGGL(k_hist, dim3((NE+255)/256), dim3(256), 0, stream, ei, counts, rank);
    hipLaunchKernelGGL(k_s1, dim3(49), dim3(256), 0, stream, counts, bsum);
    hipLaunchKernelGGL(k_s2, dim3(1), dim3(128), 0, stream,
                       bsum, boff, rowptr, We1, ae1, We2, ae2, wdot);
    hipLaunchKernelGGL(k_s3, dim3(49), dim3(256), 0, stream, counts, boff, rowptr);
    hipLaunchKernelGGL(k_scatter, dim3((NE+255)/256), dim3(256), 0, stream,
                       ei, ea, bng, bnb, bnm, bnv, rowptr, rank, edges);
    hipLaunchKernelGGL(k1_node1, dim3(1024), dim3(256), 0, stream,
                       x, W1, as1, ad1, h1h, as1n, ad1n);
    hipLaunchKernelGGL(kA1, dim3(NN/4), dim3(256), 0, stream,
                       rowptr, edges, as1n, ad1n, wdot, h1h, b1, W2, as2, ad2,
                       h2h, as2n, ad2n);
    hipLaunchKernelGGL(kA2, dim3(NN/4), dim3(256), 0, stream,
                       rowptr, edges, as2n, ad2n, wdot, h2h, b2, Wd1, bd1, Wd2, bd2,
                       out);
}

// Round 6
// 395.167 us; speedup vs baseline: 4.2701x; 1.0446x over previous
//
#include <hip/hip_runtime.h>
#include <hip/hip_fp16.h>
#include <math.h>

#define NN 100000
#define NE 1600000

// ---------- CSR build: hist with rank recording ----------
__global__ void k_hist(const int* __restrict__ ei, int* __restrict__ counts,
                       int* __restrict__ rank) {
    int e = blockIdx.x * blockDim.x + threadIdx.x;
    if (e < NE) rank[e] = atomicAdd(&counts[ei[NE + e]], 1);
}

__global__ void k_s1(const int* __restrict__ counts, int* __restrict__ bsum) {
    __shared__ int sd[256];
    int tid = threadIdx.x, b = blockIdx.x;
    int base = b * 2048 + tid * 8;
    int s = 0;
    #pragma unroll
    for (int j = 0; j < 8; ++j) {
        int g = base + j;
        s += (g < NN) ? counts[g] : 0;
    }
    sd[tid] = s;
    __syncthreads();
    for (int d = 128; d; d >>= 1) {
        if (tid < d) sd[tid] += sd[tid + d];
        __syncthreads();
    }
    if (tid == 0) bsum[b] = sd[0];
}

__global__ void k_s2(const int* __restrict__ bsum, int* __restrict__ boff,
                     int* __restrict__ rowptr,
                     const float* __restrict__ We1, const float* __restrict__ ae1,
                     const float* __restrict__ We2, const float* __restrict__ ae2,
                     float* __restrict__ wdot) {
    int t = threadIdx.x;
    if (t == 0) {
        int run = 0;
        for (int b = 0; b < 49; ++b) { boff[b] = run; run += bsum[b]; }
        rowptr[NN] = NE;
    }
    if (t >= 64 && t < 68) {
        int h = t - 64;
        float s = 0.f;
        for (int c = 0; c < 32; ++c) s += We1[h*32+c] * ae1[h*32+c];
        wdot[h] = s;
    } else if (t == 68) {
        float s = 0.f;
        for (int c = 0; c < 32; ++c) s += We2[c] * ae2[c];
        wdot[4] = s;
    }
}

__global__ void k_s3(const int* __restrict__ counts, const int* __restrict__ boff,
                     int* __restrict__ rowptr) {
    __shared__ int sT[256];
    int tid = threadIdx.x, b = blockIdx.x;
    int base = b * 2048 + tid * 8;
    int c[8];
    int s = 0;
    #pragma unroll
    for (int j = 0; j < 8; ++j) {
        int g = base + j;
        c[j] = (g < NN) ? counts[g] : 0;
        s += c[j];
    }
    sT[tid] = s;
    __syncthreads();
    for (int d = 1; d < 256; d <<= 1) {
        int v = (tid >= d) ? sT[tid - d] : 0;
        __syncthreads();
        sT[tid] += v;
        __syncthreads();
    }
    int run = (tid ? sT[tid - 1] : 0) + boff[b];
    #pragma unroll
    for (int j = 0; j < 8; ++j) {
        int g = base + j;
        if (g < NN) rowptr[g] = run;
        run += c[j];
    }
}

__global__ void k_scatter(const int* __restrict__ ei, const float* __restrict__ ea,
                          const float* __restrict__ g, const float* __restrict__ b,
                          const float* __restrict__ m, const float* __restrict__ v,
                          const int* __restrict__ rowptr, const int* __restrict__ rank,
                          int2* __restrict__ edges) {
    int e = blockIdx.x * blockDim.x + threadIdx.x;
    if (e >= NE) return;
    int dst = ei[NE + e];
    int pos = rowptr[dst] + rank[e];
    float en = (log1pf(ea[e]) - m[0]) * rsqrtf(v[0] + 1e-5f) * g[0] + b[0];
    edges[pos] = make_int2(ei[e], __float_as_int(en));
}

// ---------- node transform L1: channel-pair layout, h1 packed fp16 ----------
__global__ void __launch_bounds__(256, 2)
k1_node1(const float* __restrict__ x, const float* __restrict__ W1,
         const float* __restrict__ as1, const float* __restrict__ ad1,
         __half2* __restrict__ h1h, float* __restrict__ as1n,
         float* __restrict__ ad1n) {
    int tid = threadIdx.x, wid = tid >> 6, lane = tid & 63;
    float wc0[64], wc1[64];
    #pragma unroll
    for (int k = 0; k < 64; ++k) {
        wc0[k] = W1[k*128 + 2*lane];
        wc1[k] = W1[k*128 + 2*lane + 1];
    }
    float asc0 = as1[2*lane], asc1 = as1[2*lane+1];
    float adc0 = ad1[2*lane], adc1 = ad1[2*lane+1];
    int gw = (blockIdx.x << 2) + wid;
    int nw = gridDim.x << 2;
    for (int n = gw; n < NN; n += nw) {
        int nu = __builtin_amdgcn_readfirstlane(n);
        const float* xr = x + (size_t)nu * 64;
        float a0 = 0.f, a1 = 0.f;
        #pragma unroll
        for (int k = 0; k < 64; ++k) {
            float xk = xr[k];
            a0 = fmaf(xk, wc0[k], a0);
            a1 = fmaf(xk, wc1[k], a1);
        }
        h1h[(size_t)nu*64 + lane] = __float22half2_rn(make_float2(a0, a1));
        float p = a0*asc0 + a1*asc1;
        float q = a0*adc0 + a1*adc1;
        #pragma unroll
        for (int d = 1; d < 16; d <<= 1) {
            p += __shfl_xor(p, d);
            q += __shfl_xor(q, d);
        }
        if ((lane & 15) == 0) {
            int h = lane >> 4;
            as1n[nu*4 + h] = p;
            ad1n[nu*4 + h] = q;
        }
    }
}

// ---------- L1 aggregate: 2 edges/iter, 4ch/lane, W2 tile as half2 ----------
__global__ void __launch_bounds__(256)
kA1(const int* __restrict__ rowptr, const int2* __restrict__ edges,
    const float* __restrict__ as1n, const float* __restrict__ ad1n,
    const float* __restrict__ wdot, const __half2* __restrict__ h1h,
    const float* __restrict__ b1, const float* __restrict__ W2,
    const float* __restrict__ as2, const float* __restrict__ ad2,
    __half2* __restrict__ h2h, float* __restrict__ as2n, float* __restrict__ ad2n) {
    __shared__ __half2 W2h[64*32];          // (k-pair, col): 8KB
    __shared__ float4 exs4[4][64];
    __shared__ int    srcl[4][64];
    __shared__ float  slot[4][128];
    int tid = threadIdx.x, wid = tid >> 6, lane = tid & 63;
    for (int i = tid; i < 2048; i += 256) {
        int k2 = i >> 5, c = i & 31;
        W2h[i] = __floats2half2_rn(W2[(2*k2)*32 + c], W2[(2*k2+1)*32 + c]);
    }
    __syncthreads();

    int n = blockIdx.x * 4 + wid;
    int row0 = rowptr[n], row1 = rowptr[n + 1];
    float4 wd  = *(const float4*)wdot;
    float4 adv = *(const float4*)&ad1n[n*4];
    int es = lane >> 5;          // edge slot (0/1)
    int cq = lane & 31;          // channel quad: channels 4cq..4cq+3
    int hq = cq >> 3;            // head of these channels
    float den0 = 0.f, den1 = 0.f, den2 = 0.f, den3 = 0.f;
    float4 acc = make_float4(0.f, 0.f, 0.f, 0.f);
    const float* exf = (const float*)&exs4[wid][0];
    const uint2* h1u = (const uint2*)h1h;

    for (int base = row0; base < row1; base += 64) {
        int j = base + lane;
        bool val = j < row1;
        int2 ep = val ? edges[j] : make_int2(0, 0);
        int sv = ep.x;
        float ev = __int_as_float(ep.y);
        float4 asv = *(const float4*)&as1n[sv*4];
        float a0 = asv.x + adv.x + ev*wd.x; a0 = fmaxf(a0, 0.2f*a0);
        float a1 = asv.y + adv.y + ev*wd.y; a1 = fmaxf(a1, 0.2f*a1);
        float a2 = asv.z + adv.z + ev*wd.z; a2 = fmaxf(a2, 0.2f*a2);
        float a3 = asv.w + adv.w + ev*wd.w; a3 = fmaxf(a3, 0.2f*a3);
        float p0 = val ? __expf(a0) : 0.f; den0 += p0;
        float p1 = val ? __expf(a1) : 0.f; den1 += p1;
        float p2 = val ? __expf(a2) : 0.f; den2 += p2;
        float p3 = val ? __expf(a3) : 0.f; den3 += p3;
        exs4[wid][lane] = make_float4(p0, p1, p2, p3);
        srcl[wid][lane] = sv;
        // same-wave LDS: in-order, no barrier

        int cnt = min(64, row1 - base);
        for (int i = 0; i < cnt; i += 2) {
            int idx = i + es;
            bool ok = idx < cnt;
            int s = srcl[wid][ok ? idx : i];
            float ex = ok ? exf[idx*4 + hq] : 0.f;
            uint2 u = h1u[(size_t)s*32 + cq];     // 4 channels, 8B
            float2 hv01 = __half22float2(*(const __half2*)&u.x);
            float2 hv23 = __half22float2(*(const __half2*)&u.y);
            acc.x = fmaf(ex, hv01.x, acc.x);
            acc.y = fmaf(ex, hv01.y, acc.y);
            acc.z = fmaf(ex, hv23.x, acc.z);
            acc.w = fmaf(ex, hv23.y, acc.w);
        }
    }
    // merge edge-slot partials, reduce denominators wave-wide
    acc.x += __shfl_xor(acc.x, 32); acc.y += __shfl_xor(acc.y, 32);
    acc.z += __shfl_xor(acc.z, 32); acc.w += __shfl_xor(acc.w, 32);
    #pragma unroll
    for (int d = 32; d; d >>= 1) {
        den0 += __shfl_xor(den0, d); den1 += __shfl_xor(den1, d);
        den2 += __shfl_xor(den2, d); den3 += __shfl_xor(den3, d);
    }
    float dh = (hq == 0) ? den0 : (hq == 1) ? den1 : (hq == 2) ? den2 : den3;
    float r = 1.f / (dh + 1e-16f);
    float4 b1v = ((const float4*)b1)[cq];
    float o0 = acc.x * r + b1v.x; o0 = o0 > 0.f ? o0 : expm1f(o0);
    float o1 = acc.y * r + b1v.y; o1 = o1 > 0.f ? o1 : expm1f(o1);
    float o2 = acc.z * r + b1v.z; o2 = o2 > 0.f ? o2 : expm1f(o2);
    float o3 = acc.w * r + b1v.w; o3 = o3 > 0.f ? o3 : expm1f(o3);
    if (es == 0) *(float4*)&slot[wid][4*cq] = make_float4(o0, o1, o2, o3);

    // h2 = elu(out1) @ W2, k-split across wave halves (es picks k-half)
    int k2base = es * 32;
    float s2 = 0.f;
    #pragma unroll
    for (int kk = 0; kk < 32; ++kk) {
        float2 wf = __half22float2(W2h[(k2base + kk)*32 + cq]);
        s2 = fmaf(slot[wid][2*(k2base + kk)],     wf.x, s2);
        s2 = fmaf(slot[wid][2*(k2base + kk) + 1], wf.y, s2);
    }
    s2 += __shfl_xor(s2, 32);
    int l4 = lane & 15;
    float za = __shfl(s2, 2*l4);
    float zb = __shfl(s2, 2*l4 + 1);
    if (lane < 16) h2h[(size_t)n*16 + l4] = __float22half2_rn(make_float2(za, zb));
    float av = s2 * as2[cq] * 0.5f;
    float dv = s2 * ad2[cq] * 0.5f;
    #pragma unroll
    for (int d = 32; d; d >>= 1) { av += __shfl_xor(av, d); dv += __shfl_xor(dv, d); }
    if (lane == 0) { as2n[n] = av; ad2n[n] = dv; }
}

// ---------- L2 aggregate (fp16 gather, 4 edges/iter) + z + decoder MLP ----------
__global__ void __launch_bounds__(256)
kA2(const int* __restrict__ rowptr, const int2* __restrict__ edges,
    const float* __restrict__ as2n, const float* __restrict__ ad2n,
    const float* __restrict__ wdot, const __half2* __restrict__ h2h,
    const float* __restrict__ b2, const float* __restrict__ Wd1,
    const float* __restrict__ bd1, const float* __restrict__ Wd2,
    const float* __restrict__ bd2, float* __restrict__ out) {
    __shared__ float Wd1s[32*32], Wd2s[32*64];
    __shared__ float pl[4][64];
    __shared__ int   srcl[4][64];
    __shared__ float zs[4][32], ts[4][32];
    int tid = threadIdx.x, wid = tid >> 6, lane = tid & 63;
    int g = lane >> 4, l4 = lane & 15;
    int half = lane >> 5, l5 = lane & 31;
    for (int i = tid; i < 1024; i += 256) Wd1s[i] = Wd1[i];
    for (int i = tid; i < 2048; i += 256) Wd2s[i] = Wd2[i];
    __syncthreads();

    int n = blockIdx.x * 4 + wid;
    int row0 = rowptr[n], row1 = rowptr[n + 1];
    float wd4 = wdot[4];
    float adn = ad2n[n];
    float den = 0.f, acc0 = 0.f, acc1 = 0.f;

    for (int base = row0; base < row1; base += 64) {
        int j = base + lane;
        bool val = j < row1;
        int2 ep = val ? edges[j] : make_int2(0, 0);
        int sv = ep.x;
        float ev = __int_as_float(ep.y);
        float a = as2n[sv] + adn + ev * wd4;
        a = fmaxf(a, 0.2f*a);
        float p = val ? __expf(a) : 0.f;
        den += p;
        pl[wid][lane] = p;
        srcl[wid][lane] = sv;

        int cnt = min(64, row1 - base);
        for (int i = 0; i < cnt; i += 4) {
            int idx = i + g;
            bool ok = idx < cnt;
            int se   = ok ? srcl[wid][idx] : 0;
            float ex = ok ? pl[wid][idx] : 0.f;
            __half2 hv = h2h[(size_t)se*16 + l4];
            float2 hf = __half22float2(hv);
            acc0 = fmaf(ex, hf.x, acc0);
            acc1 = fmaf(ex, hf.y, acc1);
        }
    }
    #pragma unroll
    for (int d = 32; d; d >>= 1) den += __shfl_xor(den, d);
    acc0 += __shfl_xor(acc0, 16); acc0 += __shfl_xor(acc0, 32);
    acc1 += __shfl_xor(acc1, 16); acc1 += __shfl_xor(acc1, 32);
    float r = 1.f / (den + 1e-16f);
    if (lane < 16) {
        float z0 = acc0 * r + b2[2*l4];
        float z1 = acc1 * r + b2[2*l4 + 1];
        *(float2*)&out[(size_t)n*32 + 2*l4] = make_float2(z0, z1);
        *(float2*)&zs[wid][2*l4] = make_float2(z0, z1);
    }
    int kk0 = half * 16;
    float t2 = 0.f;
    #pragma unroll
    for (int k = 0; k < 16; ++k)
        t2 = fmaf(zs[wid][kk0 + k], Wd1s[(kk0 + k)*32 + l5], t2);
    t2 += __shfl_xor(t2, 32);
    t2 += bd1[l5];
    t2 = t2 > 0.f ? t2 : expm1f(t2);
    if (lane < 32) ts[wid][l5] = t2;

    float xo = bd2[lane];
    #pragma unroll
    for (int k = 0; k < 32; ++k)
        xo = fmaf(ts[wid][k], Wd2s[k*64 + lane], xo);
    out[(size_t)NN*32 + (size_t)n*64 + lane] = xo;
}

extern "C" void kernel_launch(void* const* d_in, const int* in_sizes, int n_in,
                              void* d_out, int out_size, void* d_ws, size_t ws_size,
                              hipStream_t stream) {
    const float* x    = (const float*)d_in[0];
    const int*   ei   = (const int*)  d_in[1];
    const float* ea   = (const float*)d_in[2];
    const float* bng  = (const float*)d_in[3];
    const float* bnb  = (const float*)d_in[4];
    const float* bnm  = (const float*)d_in[5];
    const float* bnv  = (const float*)d_in[6];
    const float* W1   = (const float*)d_in[7];
    const float* as1  = (const float*)d_in[8];
    const float* ad1  = (const float*)d_in[9];
    const float* We1  = (const float*)d_in[10];
    const float* ae1  = (const float*)d_in[11];
    const float* b1   = (const float*)d_in[12];
    const float* W2   = (const float*)d_in[13];
    const float* as2  = (const float*)d_in[14];
    const float* ad2  = (const float*)d_in[15];
    const float* We2  = (const float*)d_in[16];
    const float* ae2  = (const float*)d_in[17];
    const float* b2   = (const float*)d_in[18];
    const float* Wd1  = (const float*)d_in[19];
    const float* bd1  = (const float*)d_in[20];
    const float* Wd2  = (const float*)d_in[21];
    const float* bd2  = (const float*)d_in[22];
    float* out = (float*)d_out;

    float* wsf   = (float*)d_ws;
    __half2* h1h = (__half2*)wsf;                    // NN*64 (25.6MB)
    float* as1n  = (float*)(h1h + (size_t)NN*64);    // NN*4
    float* ad1n  = as1n + (size_t)NN*4;              // NN*4
    __half2* h2h = (__half2*)(ad1n + (size_t)NN*4);  // NN*16
    float* as2n  = (float*)(h2h + (size_t)NN*16);    // NN
    float* ad2n  = as2n + NN;                        // NN
    float* wdot  = ad2n + NN;                        // 8
    int2*  edges = (int2*)(wdot + 8);                // NE
    int*   rank  = (int*)(edges + NE);               // NE
    int*   counts = rank + NE;                       // NN
    int*   rowptr = counts + NN;                     // NN+1
    int*   bsum   = rowptr + NN + 1;                 // 64
    int*   boff   = bsum + 64;                       // 64

    hipMemsetAsync(counts, 0, NN * sizeof(int), stream);
    hipLaunchKernelGGL(k_hist, dim3((NE+255)/256), dim3(256), 0, stream, ei, counts, rank);
    hipLaunchKernelGGL(k_s1, dim3(49), dim3(256), 0, stream, counts, bsum);
    hipLaunchKernelGGL(k_s2, dim3(1), dim3(128), 0, stream,
                       bsum, boff, rowptr, We1, ae1, We2, ae2, wdot);
    hipLaunchKernelGGL(k_s3, dim3(49), dim3(256), 0, stream, counts, boff, rowptr);
    hipLaunchKernelGGL(k_scatter, dim3((NE+255)/256), dim3(256), 0, stream,
                       ei, ea, bng, bnb, bnm, bnv, rowptr, rank, edges);
    hipLaunchKernelGGL(k1_node1, dim3(1024), dim3(256), 0, stream,
                       x, W1, as1, ad1, h1h, as1n, ad1n);
    hipLaunchKernelGGL(kA1, dim3(NN/4), dim3(256), 0, stream,
                       rowptr, edges, as1n, ad1n, wdot, h1h, b1, W2, as2, ad2,
                       h2h, as2n, ad2n);
    hipLaunchKernelGGL(kA2, dim3(NN/4), dim3(256), 0, stream,
                       rowptr, edges, as2n, ad2n, wdot, h2h, b2, Wd1, bd1, Wd2, bd2,
                       out);
}